// Round 3
// baseline (3924.609 us; speedup 1.0000x reference)
//
#include <hip/hip_runtime.h>
#include <hip/hip_bf16.h>

#define NN 100000
#define EPR 1600000
#define FIN 256
#define FOUT 64
#define NB 782            // ceil(100000/128) dst buckets of 128 nodes
#define CHUNK 4096
#define EPT 16            // edges per thread in part_kernel

// ---------------- fused: out-degree count + per-relation bucket histogram ----------------
__global__ void deg_all_kernel(const int* __restrict__ ei,
                               unsigned* __restrict__ deg_s_all,
                               unsigned* __restrict__ ghist_all) {
    int i = blockIdx.x * blockDim.x + threadIdx.x;
    int stride = gridDim.x * blockDim.x;
    for (int e = i; e < EPR; e += stride) {
        #pragma unroll
        for (int r = 0; r < 4; ++r) {
            int s = ei[(size_t)r * 2 * EPR + e];
            int d = ei[(size_t)r * 2 * EPR + EPR + e];
            atomicAdd(&deg_s_all[r * NN + s], 1u);
            atomicAdd(&ghist_all[r * NB + (d >> 7)], 1u);
        }
    }
}

__global__ void norm_all_kernel(const unsigned* __restrict__ deg_s_all,
                                float* __restrict__ ns_all) {
    int i = blockIdx.x * blockDim.x + threadIdx.x;
    if (i < 4 * NN) {
        unsigned a = deg_s_all[i]; if (a < 1u) a = 1u;
        ns_all[i] = rsqrtf((float)a);
    }
}

// ---------------- fp32 GEMM: hs[N,64] = (x[N,256] @ w[256,64]) * ns[row] ----------------
#define BM 128
#define BK 32
__global__ __launch_bounds__(256) void gemm_kernel(const float* __restrict__ x,
                                                   const float* __restrict__ w,
                                                   float* __restrict__ hs,
                                                   const float* __restrict__ ns) {
    __shared__ float xs[BK][BM];
    __shared__ float wsh[BK][FOUT];
    int tid = threadIdx.x;
    int m0 = blockIdx.x * BM;
    int tc = tid & 7;
    int tr = tid >> 3;
    float acc[4][8];
    #pragma unroll
    for (int i = 0; i < 4; i++)
        #pragma unroll
        for (int j = 0; j < 8; j++) acc[i][j] = 0.f;

    for (int k0 = 0; k0 < FIN; k0 += BK) {
        #pragma unroll
        for (int t = 0; t < 4; ++t) {
            int f = tid * 4 + t;
            int row = f >> 3;
            int kp = (f & 7) << 2;
            int gr = m0 + row;
            const float4 v = *(const float4*)&x[(size_t)(gr < NN ? gr : 0) * FIN + k0 + kp];
            xs[kp + 0][row] = v.x;
            xs[kp + 1][row] = v.y;
            xs[kp + 2][row] = v.z;
            xs[kp + 3][row] = v.w;
        }
        #pragma unroll
        for (int t = 0; t < 2; ++t) {
            int f = tid * 2 + t;
            int kk = f >> 4;
            int c = (f & 15) << 2;
            *(float4*)&wsh[kk][c] = *(const float4*)&w[(size_t)(k0 + kk) * FOUT + c];
        }
        __syncthreads();
        #pragma unroll
        for (int k = 0; k < BK; ++k) {
            float4 xv = *(const float4*)&xs[k][tr * 4];
            float4 w0 = *(const float4*)&wsh[k][tc * 8];
            float4 w1 = *(const float4*)&wsh[k][tc * 8 + 4];
            float xa[4] = {xv.x, xv.y, xv.z, xv.w};
            float wb[8] = {w0.x, w0.y, w0.z, w0.w, w1.x, w1.y, w1.z, w1.w};
            #pragma unroll
            for (int i = 0; i < 4; i++)
                #pragma unroll
                for (int j = 0; j < 8; j++)
                    acc[i][j] = fmaf(xa[i], wb[j], acc[i][j]);
        }
        __syncthreads();
    }
    #pragma unroll
    for (int i = 0; i < 4; i++) {
        int gr = m0 + tr * 4 + i;
        if (gr < NN) {
            float sc = ns[gr];
            float4 o0 = {acc[i][0] * sc, acc[i][1] * sc, acc[i][2] * sc, acc[i][3] * sc};
            float4 o1 = {acc[i][4] * sc, acc[i][5] * sc, acc[i][6] * sc, acc[i][7] * sc};
            *(float4*)&hs[(size_t)gr * FOUT + tc * 8] = o0;
            *(float4*)&hs[(size_t)gr * FOUT + tc * 8 + 4] = o1;
        }
    }
}

// ---------------- exclusive scan of the 782 bucket counts (one block) ----------------
__global__ void scan_nb_kernel(const unsigned* __restrict__ ghist,
                               unsigned* __restrict__ gbase, unsigned* __restrict__ gcur) {
    __shared__ unsigned sc[256];
    int tid = threadIdx.x;
    unsigned loc[4]; unsigned s = 0;
    #pragma unroll
    for (int k = 0; k < 4; ++k) {
        int idx = tid * 4 + k;
        unsigned v = (idx < NB) ? ghist[idx] : 0u;
        loc[k] = s; s += v;
    }
    sc[tid] = s; __syncthreads();
    for (int off = 1; off < 256; off <<= 1) {
        unsigned a = (tid >= off) ? sc[tid - off] : 0u;
        __syncthreads(); sc[tid] += a; __syncthreads();
    }
    unsigned texcl = tid ? sc[tid - 1] : 0u;
    #pragma unroll
    for (int k = 0; k < 4; ++k) {
        int idx = tid * 4 + k;
        if (idx < NB) { gbase[idx] = texcl + loc[k]; gcur[idx] = texcl + loc[k]; }
    }
}

// ---------------- partition: bucket edges by dst>>7, coalesced packed output ----------------
__global__ __launch_bounds__(256) void part_kernel(const int* __restrict__ src,
                                                   const int* __restrict__ dst,
                                                   unsigned* __restrict__ gcur,
                                                   unsigned* __restrict__ pairs, int nE) {
    __shared__ unsigned h[NB];      // histogram, then reused as local cursor
    __shared__ unsigned hloc[NB];   // exclusive scan (local slot base)
    __shared__ unsigned hbase[NB];  // reserved global base
    __shared__ unsigned sc[256];
    __shared__ unsigned buf[CHUNK];   // packed records in bucket-local order
    __shared__ unsigned buf2[CHUNK];  // global positions
    int tid = threadIdx.x;
    int e0 = blockIdx.x * CHUNK;
    int csize = nE - e0; if (csize > CHUNK) csize = CHUNK;

    for (int i = tid; i < NB; i += 256) h[i] = 0;
    __syncthreads();

    int es[EPT], ed[EPT];
    #pragma unroll
    for (int t = 0; t < EPT; ++t) {
        int e = e0 + t * 256 + tid;
        if (e < nE) {
            es[t] = src[e]; ed[t] = dst[e];
            atomicAdd(&h[ed[t] >> 7], 1u);
        } else { es[t] = -1; ed[t] = 0; }
    }
    __syncthreads();

    // block scan of h -> hloc (exclusive)
    unsigned loc[4]; unsigned s = 0;
    #pragma unroll
    for (int k = 0; k < 4; ++k) {
        int idx = tid * 4 + k;
        unsigned v = (idx < NB) ? h[idx] : 0u;
        loc[k] = s; s += v;
    }
    sc[tid] = s; __syncthreads();
    for (int off = 1; off < 256; off <<= 1) {
        unsigned a = (tid >= off) ? sc[tid - off] : 0u;
        __syncthreads(); sc[tid] += a; __syncthreads();
    }
    unsigned texcl = tid ? sc[tid - 1] : 0u;
    #pragma unroll
    for (int k = 0; k < 4; ++k) {
        int idx = tid * 4 + k;
        if (idx < NB) hloc[idx] = texcl + loc[k];
    }
    __syncthreads();

    // reserve global space per bucket
    for (int i = tid; i < NB; i += 256) {
        unsigned c = h[i];
        hbase[i] = c ? atomicAdd(&gcur[i], c) : 0u;
    }
    __syncthreads();
    for (int i = tid; i < NB; i += 256) h[i] = 0;   // reuse as local cursor
    __syncthreads();

    // place into LDS in bucket-local order
    #pragma unroll
    for (int t = 0; t < EPT; ++t) {
        if (es[t] >= 0) {
            int b = ed[t] >> 7;
            unsigned r = atomicAdd(&h[b], 1u);
            unsigned slot = hloc[b] + r;
            buf[slot] = (unsigned)es[t] | ((unsigned)(ed[t] & 127) << 17);
            buf2[slot] = hbase[b] + r;
        }
    }
    __syncthreads();

    // stream out (coalesced within bucket runs)
    for (int k = tid; k < csize; k += 256)
        pairs[buf2[k]] = buf[k];
}

// ---------------- aggregation: one block per bucket, LDS accumulator ----------------
template<bool LAST>
__global__ __launch_bounds__(256) void agg_kernel(const unsigned* __restrict__ pairs,
                                                  const unsigned* __restrict__ gbase,
                                                  const unsigned* __restrict__ ghist,
                                                  const float* __restrict__ hs,
                                                  float* __restrict__ out) {
    __shared__ float acc[128][FOUT];   // 32 KB
    __shared__ unsigned cnt[128];
    int tid = threadIdx.x;
    int b = blockIdx.x;
    int wave = tid >> 6, lane = tid & 63;

    for (int i = tid; i < 128 * FOUT / 4; i += 256) ((float4*)acc)[i] = make_float4(0, 0, 0, 0);
    if (tid < 128) cnt[tid] = 0;
    __syncthreads();

    unsigned start = gbase[b];
    int n = (int)ghist[b];
    for (int base = wave * 64; base < n; base += 256) {
        int m = n - base; if (m > 64) m = 64;
        unsigned p = 0;
        if (base + lane < n) {
            p = pairs[start + base + lane];
            atomicAdd(&cnt[p >> 17], 1u);    // in-degree
        }
        for (int j = 0; j < m; ++j) {
            unsigned u = __shfl(p, j);
            int s = u & 0x1FFFF;
            int dl = u >> 17;
            atomicAdd(&acc[dl][lane], hs[(size_t)s * FOUT + lane]);
        }
    }
    __syncthreads();

    #pragma unroll 4
    for (int i = 0; i < 32; ++i) {
        int nl = wave * 32 + i;
        int node = b * 128 + nl;
        if (node < NN) {
            unsigned c = cnt[nl]; if (c < 1u) c = 1u;
            float ndv = rsqrtf((float)c);
            size_t oi = (size_t)node * FOUT + lane;
            float r = out[oi] + acc[nl][lane] * ndv;
            out[oi] = LAST ? tanhf(r) : r;
        }
    }
}

extern "C" void kernel_launch(void* const* d_in, const int* in_sizes, int n_in,
                              void* d_out, int out_size, void* d_ws, size_t ws_size,
                              hipStream_t stream) {
    const float* x = (const float*)d_in[0];
    const float* W = (const float*)d_in[1];
    const int* ei = (const int*)d_in[2];
    float* out = (float*)d_out;

    char* ws = (char*)d_ws;
    size_t o = 0;
    float* hs = (float*)(ws + o);           o += (size_t)NN * FOUT * 4;       // 25.6 MB
    unsigned* pairs = (unsigned*)(ws + o);  o += (size_t)EPR * 4;             // 6.4 MB
    unsigned* deg_s_all = (unsigned*)(ws + o); o += (size_t)4 * NN * 4;       // 1.6 MB
    unsigned* ghist_all = (unsigned*)(ws + o); o += (size_t)4 * NB * 4;       // contiguous w/ deg for memset
    float* ns_all = (float*)(ws + o);       o += (size_t)4 * NN * 4;          // 1.6 MB
    unsigned* gbase = (unsigned*)(ws + o);  o += (size_t)NB * 4;
    unsigned* gcur = (unsigned*)(ws + o);   o += (size_t)NB * 4;

    hipMemsetAsync(deg_s_all, 0, (size_t)(4 * NN + 4 * NB) * 4, stream);
    hipMemsetAsync(d_out, 0, (size_t)out_size * sizeof(float), stream);

    deg_all_kernel<<<2048, 256, 0, stream>>>(ei, deg_s_all, ghist_all);
    norm_all_kernel<<<(4 * NN + 255) / 256, 256, 0, stream>>>(deg_s_all, ns_all);

    for (int r = 0; r < 4; ++r) {
        const int* src = ei + (size_t)r * 2 * EPR;
        const int* dst = src + EPR;
        const float* w = W + (size_t)r * FIN * FOUT;

        gemm_kernel<<<(NN + BM - 1) / BM, 256, 0, stream>>>(x, w, hs, ns_all + (size_t)r * NN);
        scan_nb_kernel<<<1, 256, 0, stream>>>(ghist_all + (size_t)r * NB, gbase, gcur);
        part_kernel<<<(EPR + CHUNK - 1) / CHUNK, 256, 0, stream>>>(src, dst, gcur, pairs, EPR);
        if (r == 3)
            agg_kernel<true><<<NB, 256, 0, stream>>>(pairs, gbase, ghist_all + (size_t)r * NB, hs, out);
        else
            agg_kernel<false><<<NB, 256, 0, stream>>>(pairs, gbase, ghist_all + (size_t)r * NB, hs, out);
    }
}

// Round 4
// 3809.357 us; speedup vs baseline: 1.0303x; 1.0303x over previous
//
#include <hip/hip_runtime.h>
#include <hip/hip_bf16.h>

#define NN 100000
#define EPR 1600000
#define FIN 256
#define FOUT 64
#define NB 782            // ceil(100000/128) dst buckets of 128 nodes
#define CHUNK 4096
#define EPT 16            // edges per thread in part_kernel

// ---------------- fused: out-degree count + per-relation bucket histogram ----------------
__global__ void deg_all_kernel(const int* __restrict__ ei,
                               unsigned* __restrict__ deg_s_all,
                               unsigned* __restrict__ ghist_all) {
    int i = blockIdx.x * blockDim.x + threadIdx.x;
    int stride = gridDim.x * blockDim.x;
    for (int e = i; e < EPR; e += stride) {
        #pragma unroll
        for (int r = 0; r < 4; ++r) {
            int s = ei[(size_t)r * 2 * EPR + e];
            int d = ei[(size_t)r * 2 * EPR + EPR + e];
            atomicAdd(&deg_s_all[r * NN + s], 1u);
            atomicAdd(&ghist_all[r * NB + (d >> 7)], 1u);
        }
    }
}

__global__ void norm_all_kernel(const unsigned* __restrict__ deg_s_all,
                                float* __restrict__ ns_all) {
    int i = blockIdx.x * blockDim.x + threadIdx.x;
    if (i < 4 * NN) {
        unsigned a = deg_s_all[i]; if (a < 1u) a = 1u;
        ns_all[i] = rsqrtf((float)a);
    }
}

// ---------------- fp32 GEMM: hs[N,64] = (x[N,256] @ w[256,64]) * ns[row] ----------------
#define BM 128
#define BK 32
__global__ __launch_bounds__(256) void gemm_kernel(const float* __restrict__ x,
                                                   const float* __restrict__ w,
                                                   float* __restrict__ hs,
                                                   const float* __restrict__ ns) {
    __shared__ float xs[BK][BM];
    __shared__ float wsh[BK][FOUT];
    int tid = threadIdx.x;
    int m0 = blockIdx.x * BM;
    int tc = tid & 7;
    int tr = tid >> 3;
    float acc[4][8];
    #pragma unroll
    for (int i = 0; i < 4; i++)
        #pragma unroll
        for (int j = 0; j < 8; j++) acc[i][j] = 0.f;

    for (int k0 = 0; k0 < FIN; k0 += BK) {
        #pragma unroll
        for (int t = 0; t < 4; ++t) {
            int f = tid * 4 + t;
            int row = f >> 3;
            int kp = (f & 7) << 2;
            int gr = m0 + row;
            const float4 v = *(const float4*)&x[(size_t)(gr < NN ? gr : 0) * FIN + k0 + kp];
            xs[kp + 0][row] = v.x;
            xs[kp + 1][row] = v.y;
            xs[kp + 2][row] = v.z;
            xs[kp + 3][row] = v.w;
        }
        #pragma unroll
        for (int t = 0; t < 2; ++t) {
            int f = tid * 2 + t;
            int kk = f >> 4;
            int c = (f & 15) << 2;
            *(float4*)&wsh[kk][c] = *(const float4*)&w[(size_t)(k0 + kk) * FOUT + c];
        }
        __syncthreads();
        #pragma unroll
        for (int k = 0; k < BK; ++k) {
            float4 xv = *(const float4*)&xs[k][tr * 4];
            float4 w0 = *(const float4*)&wsh[k][tc * 8];
            float4 w1 = *(const float4*)&wsh[k][tc * 8 + 4];
            float xa[4] = {xv.x, xv.y, xv.z, xv.w};
            float wb[8] = {w0.x, w0.y, w0.z, w0.w, w1.x, w1.y, w1.z, w1.w};
            #pragma unroll
            for (int i = 0; i < 4; i++)
                #pragma unroll
                for (int j = 0; j < 8; j++)
                    acc[i][j] = fmaf(xa[i], wb[j], acc[i][j]);
        }
        __syncthreads();
    }
    #pragma unroll
    for (int i = 0; i < 4; i++) {
        int gr = m0 + tr * 4 + i;
        if (gr < NN) {
            float sc = ns[gr];
            float4 o0 = {acc[i][0] * sc, acc[i][1] * sc, acc[i][2] * sc, acc[i][3] * sc};
            float4 o1 = {acc[i][4] * sc, acc[i][5] * sc, acc[i][6] * sc, acc[i][7] * sc};
            *(float4*)&hs[(size_t)gr * FOUT + tc * 8] = o0;
            *(float4*)&hs[(size_t)gr * FOUT + tc * 8 + 4] = o1;
        }
    }
}

// ---------------- exclusive scan of the 782 bucket counts (one block) ----------------
__global__ void scan_nb_kernel(const unsigned* __restrict__ ghist,
                               unsigned* __restrict__ gbase, unsigned* __restrict__ gcur) {
    __shared__ unsigned sc[256];
    int tid = threadIdx.x;
    unsigned loc[4]; unsigned s = 0;
    #pragma unroll
    for (int k = 0; k < 4; ++k) {
        int idx = tid * 4 + k;
        unsigned v = (idx < NB) ? ghist[idx] : 0u;
        loc[k] = s; s += v;
    }
    sc[tid] = s; __syncthreads();
    for (int off = 1; off < 256; off <<= 1) {
        unsigned a = (tid >= off) ? sc[tid - off] : 0u;
        __syncthreads(); sc[tid] += a; __syncthreads();
    }
    unsigned texcl = tid ? sc[tid - 1] : 0u;
    #pragma unroll
    for (int k = 0; k < 4; ++k) {
        int idx = tid * 4 + k;
        if (idx < NB) { gbase[idx] = texcl + loc[k]; gcur[idx] = texcl + loc[k]; }
    }
}

// ---------------- partition: bucket edges by dst>>7, coalesced packed output ----------------
__global__ __launch_bounds__(256) void part_kernel(const int* __restrict__ src,
                                                   const int* __restrict__ dst,
                                                   unsigned* __restrict__ gcur,
                                                   unsigned* __restrict__ pairs, int nE) {
    __shared__ unsigned h[NB];      // histogram, then reused as local cursor
    __shared__ unsigned hloc[NB];   // exclusive scan (local slot base)
    __shared__ unsigned hbase[NB];  // reserved global base
    __shared__ unsigned sc[256];
    __shared__ unsigned buf[CHUNK];   // packed records in bucket-local order
    __shared__ unsigned buf2[CHUNK];  // global positions
    int tid = threadIdx.x;
    int e0 = blockIdx.x * CHUNK;
    int csize = nE - e0; if (csize > CHUNK) csize = CHUNK;

    for (int i = tid; i < NB; i += 256) h[i] = 0;
    __syncthreads();

    int es[EPT], ed[EPT];
    #pragma unroll
    for (int t = 0; t < EPT; ++t) {
        int e = e0 + t * 256 + tid;
        if (e < nE) {
            es[t] = src[e]; ed[t] = dst[e];
            atomicAdd(&h[ed[t] >> 7], 1u);
        } else { es[t] = -1; ed[t] = 0; }
    }
    __syncthreads();

    // block scan of h -> hloc (exclusive)
    unsigned loc[4]; unsigned s = 0;
    #pragma unroll
    for (int k = 0; k < 4; ++k) {
        int idx = tid * 4 + k;
        unsigned v = (idx < NB) ? h[idx] : 0u;
        loc[k] = s; s += v;
    }
    sc[tid] = s; __syncthreads();
    for (int off = 1; off < 256; off <<= 1) {
        unsigned a = (tid >= off) ? sc[tid - off] : 0u;
        __syncthreads(); sc[tid] += a; __syncthreads();
    }
    unsigned texcl = tid ? sc[tid - 1] : 0u;
    #pragma unroll
    for (int k = 0; k < 4; ++k) {
        int idx = tid * 4 + k;
        if (idx < NB) hloc[idx] = texcl + loc[k];
    }
    __syncthreads();

    // reserve global space per bucket
    for (int i = tid; i < NB; i += 256) {
        unsigned c = h[i];
        hbase[i] = c ? atomicAdd(&gcur[i], c) : 0u;
    }
    __syncthreads();
    for (int i = tid; i < NB; i += 256) h[i] = 0;   // reuse as local cursor
    __syncthreads();

    // place into LDS in bucket-local order
    #pragma unroll
    for (int t = 0; t < EPT; ++t) {
        if (es[t] >= 0) {
            int b = ed[t] >> 7;
            unsigned r = atomicAdd(&h[b], 1u);
            unsigned slot = hloc[b] + r;
            buf[slot] = (unsigned)es[t] | ((unsigned)(ed[t] & 127) << 17);
            buf2[slot] = hbase[b] + r;
        }
    }
    __syncthreads();

    // stream out (coalesced within bucket runs)
    for (int k = tid; k < csize; k += 256)
        pairs[buf2[k]] = buf[k];
}

// ---------------- aggregation: one block per bucket, LDS accumulator ----------------
// 512 threads (8 waves); fixed 64-iteration inner loop, unrolled x8 so 8 gathers
// are in flight per wave. Invalid lanes use a dummy record -> trash row 128.
template<bool LAST>
__global__ __launch_bounds__(512) void agg_kernel(const unsigned* __restrict__ pairs,
                                                  const unsigned* __restrict__ gbase,
                                                  const unsigned* __restrict__ ghist,
                                                  const float* __restrict__ hs,
                                                  float* __restrict__ out) {
    __shared__ float acc[129][FOUT];   // row 128 = trash row for padded lanes
    __shared__ unsigned cnt[128];
    int tid = threadIdx.x;
    int b = blockIdx.x;
    int wave = tid >> 6, lane = tid & 63;

    for (int i = tid; i < 129 * FOUT / 4; i += 512) ((float4*)acc)[i] = make_float4(0, 0, 0, 0);
    if (tid < 128) cnt[tid] = 0;
    __syncthreads();

    unsigned start = gbase[b];
    int n = (int)ghist[b];
    const unsigned DUMMY = 0u | (128u << 17);   // src=0 (safe addr), dl=128 (trash row)
    for (int base = wave * 64; base < n; base += 512) {
        unsigned p = DUMMY;
        if (base + lane < n) {
            p = pairs[start + base + lane];
            atomicAdd(&cnt[p >> 17], 1u);    // in-degree (real edges only)
        }
        #pragma unroll
        for (int jo = 0; jo < 64; jo += 8) {
            float v[8]; int dl[8];
            #pragma unroll
            for (int u = 0; u < 8; ++u) {
                unsigned q = __shfl(p, jo + u);
                dl[u] = q >> 17;
                v[u] = hs[(size_t)(q & 0x1FFFF) * FOUT + lane];
            }
            #pragma unroll
            for (int u = 0; u < 8; ++u)
                atomicAdd(&acc[dl[u]][lane], v[u]);
        }
    }
    __syncthreads();

    #pragma unroll 4
    for (int i = 0; i < 16; ++i) {
        int nl = wave * 16 + i;
        int node = b * 128 + nl;
        if (node < NN) {
            unsigned c = cnt[nl]; if (c < 1u) c = 1u;
            float ndv = rsqrtf((float)c);
            size_t oi = (size_t)node * FOUT + lane;
            float r = out[oi] + acc[nl][lane] * ndv;
            out[oi] = LAST ? tanhf(r) : r;
        }
    }
}

extern "C" void kernel_launch(void* const* d_in, const int* in_sizes, int n_in,
                              void* d_out, int out_size, void* d_ws, size_t ws_size,
                              hipStream_t stream) {
    const float* x = (const float*)d_in[0];
    const float* W = (const float*)d_in[1];
    const int* ei = (const int*)d_in[2];
    float* out = (float*)d_out;

    char* ws = (char*)d_ws;
    size_t o = 0;
    float* hs = (float*)(ws + o);           o += (size_t)NN * FOUT * 4;       // 25.6 MB
    unsigned* pairs = (unsigned*)(ws + o);  o += (size_t)EPR * 4;             // 6.4 MB
    unsigned* deg_s_all = (unsigned*)(ws + o); o += (size_t)4 * NN * 4;       // 1.6 MB
    unsigned* ghist_all = (unsigned*)(ws + o); o += (size_t)4 * NB * 4;       // contiguous w/ deg for memset
    float* ns_all = (float*)(ws + o);       o += (size_t)4 * NN * 4;          // 1.6 MB
    unsigned* gbase = (unsigned*)(ws + o);  o += (size_t)NB * 4;
    unsigned* gcur = (unsigned*)(ws + o);   o += (size_t)NB * 4;

    hipMemsetAsync(deg_s_all, 0, (size_t)(4 * NN + 4 * NB) * 4, stream);
    hipMemsetAsync(d_out, 0, (size_t)out_size * sizeof(float), stream);

    deg_all_kernel<<<2048, 256, 0, stream>>>(ei, deg_s_all, ghist_all);
    norm_all_kernel<<<(4 * NN + 255) / 256, 256, 0, stream>>>(deg_s_all, ns_all);

    for (int r = 0; r < 4; ++r) {
        const int* src = ei + (size_t)r * 2 * EPR;
        const int* dst = src + EPR;
        const float* w = W + (size_t)r * FIN * FOUT;

        gemm_kernel<<<(NN + BM - 1) / BM, 256, 0, stream>>>(x, w, hs, ns_all + (size_t)r * NN);
        scan_nb_kernel<<<1, 256, 0, stream>>>(ghist_all + (size_t)r * NB, gbase, gcur);
        part_kernel<<<(EPR + CHUNK - 1) / CHUNK, 256, 0, stream>>>(src, dst, gcur, pairs, EPR);
        if (r == 3)
            agg_kernel<true><<<NB, 512, 0, stream>>>(pairs, gbase, ghist_all + (size_t)r * NB, hs, out);
        else
            agg_kernel<false><<<NB, 512, 0, stream>>>(pairs, gbase, ghist_all + (size_t)r * NB, hs, out);
    }
}

// Round 5
// 3344.666 us; speedup vs baseline: 1.1734x; 1.1389x over previous
//
#include <hip/hip_runtime.h>
#include <hip/hip_bf16.h>

#define NN 100000
#define EPR 1600000
#define FIN 256
#define FOUT 64
#define BSZ 64            // dst nodes per bucket
#define NB 1563           // ceil(100000/64)
#define CHUNK 4096
#define EPT 16            // edges per thread in part_kernel

// ---------------- fused: out-degree count + per-relation bucket histogram ----------------
__global__ void deg_all_kernel(const int* __restrict__ ei,
                               unsigned* __restrict__ deg_s_all,
                               unsigned* __restrict__ ghist_all) {
    int i = blockIdx.x * blockDim.x + threadIdx.x;
    int stride = gridDim.x * blockDim.x;
    for (int e = i; e < EPR; e += stride) {
        #pragma unroll
        for (int r = 0; r < 4; ++r) {
            int s = ei[(size_t)r * 2 * EPR + e];
            int d = ei[(size_t)r * 2 * EPR + EPR + e];
            atomicAdd(&deg_s_all[r * NN + s], 1u);
            atomicAdd(&ghist_all[r * NB + (d >> 6)], 1u);
        }
    }
}

__global__ void norm_all_kernel(const unsigned* __restrict__ deg_s_all,
                                float* __restrict__ ns_all) {
    int i = blockIdx.x * blockDim.x + threadIdx.x;
    if (i < 4 * NN) {
        unsigned a = deg_s_all[i]; if (a < 1u) a = 1u;
        ns_all[i] = rsqrtf((float)a);
    }
}

// ---------------- fp32 GEMM: hs[N,64] = (x[N,256] @ w[256,64]) * ns[row] ----------------
#define BM 128
#define BK 32
__global__ __launch_bounds__(256) void gemm_kernel(const float* __restrict__ x,
                                                   const float* __restrict__ w,
                                                   float* __restrict__ hs,
                                                   const float* __restrict__ ns) {
    __shared__ float xs[BK][BM];
    __shared__ float wsh[BK][FOUT];
    int tid = threadIdx.x;
    int m0 = blockIdx.x * BM;
    int tc = tid & 7;
    int tr = tid >> 3;
    float acc[4][8];
    #pragma unroll
    for (int i = 0; i < 4; i++)
        #pragma unroll
        for (int j = 0; j < 8; j++) acc[i][j] = 0.f;

    for (int k0 = 0; k0 < FIN; k0 += BK) {
        #pragma unroll
        for (int t = 0; t < 4; ++t) {
            int f = tid * 4 + t;
            int row = f >> 3;
            int kp = (f & 7) << 2;
            int gr = m0 + row;
            const float4 v = *(const float4*)&x[(size_t)(gr < NN ? gr : 0) * FIN + k0 + kp];
            xs[kp + 0][row] = v.x;
            xs[kp + 1][row] = v.y;
            xs[kp + 2][row] = v.z;
            xs[kp + 3][row] = v.w;
        }
        #pragma unroll
        for (int t = 0; t < 2; ++t) {
            int f = tid * 2 + t;
            int kk = f >> 4;
            int c = (f & 15) << 2;
            *(float4*)&wsh[kk][c] = *(const float4*)&w[(size_t)(k0 + kk) * FOUT + c];
        }
        __syncthreads();
        #pragma unroll
        for (int k = 0; k < BK; ++k) {
            float4 xv = *(const float4*)&xs[k][tr * 4];
            float4 w0 = *(const float4*)&wsh[k][tc * 8];
            float4 w1 = *(const float4*)&wsh[k][tc * 8 + 4];
            float xa[4] = {xv.x, xv.y, xv.z, xv.w};
            float wb[8] = {w0.x, w0.y, w0.z, w0.w, w1.x, w1.y, w1.z, w1.w};
            #pragma unroll
            for (int i = 0; i < 4; i++)
                #pragma unroll
                for (int j = 0; j < 8; j++)
                    acc[i][j] = fmaf(xa[i], wb[j], acc[i][j]);
        }
        __syncthreads();
    }
    #pragma unroll
    for (int i = 0; i < 4; i++) {
        int gr = m0 + tr * 4 + i;
        if (gr < NN) {
            float sc = ns[gr];
            float4 o0 = {acc[i][0] * sc, acc[i][1] * sc, acc[i][2] * sc, acc[i][3] * sc};
            float4 o1 = {acc[i][4] * sc, acc[i][5] * sc, acc[i][6] * sc, acc[i][7] * sc};
            *(float4*)&hs[(size_t)gr * FOUT + tc * 8] = o0;
            *(float4*)&hs[(size_t)gr * FOUT + tc * 8 + 4] = o1;
        }
    }
}

// ---------------- exclusive scan of the NB bucket counts (one block) ----------------
__global__ void scan_nb_kernel(const unsigned* __restrict__ ghist,
                               unsigned* __restrict__ gbase, unsigned* __restrict__ gcur) {
    __shared__ unsigned sc[256];
    int tid = threadIdx.x;
    unsigned loc[8]; unsigned s = 0;
    #pragma unroll
    for (int k = 0; k < 8; ++k) {
        int idx = tid * 8 + k;
        unsigned v = (idx < NB) ? ghist[idx] : 0u;
        loc[k] = s; s += v;
    }
    sc[tid] = s; __syncthreads();
    for (int off = 1; off < 256; off <<= 1) {
        unsigned a = (tid >= off) ? sc[tid - off] : 0u;
        __syncthreads(); sc[tid] += a; __syncthreads();
    }
    unsigned texcl = tid ? sc[tid - 1] : 0u;
    #pragma unroll
    for (int k = 0; k < 8; ++k) {
        int idx = tid * 8 + k;
        if (idx < NB) { gbase[idx] = texcl + loc[k]; gcur[idx] = texcl + loc[k]; }
    }
}

// ---------------- partition: bucket edges by dst>>6, coalesced packed output ----------------
__global__ __launch_bounds__(256) void part_kernel(const int* __restrict__ src,
                                                   const int* __restrict__ dst,
                                                   unsigned* __restrict__ gcur,
                                                   unsigned* __restrict__ pairs, int nE) {
    __shared__ unsigned h[NB];      // histogram, then reused as local cursor
    __shared__ unsigned hloc[NB];   // exclusive scan (local slot base)
    __shared__ unsigned hbase[NB];  // reserved global base
    __shared__ unsigned sc[256];
    __shared__ unsigned buf[CHUNK];   // packed records in bucket-local order
    __shared__ unsigned buf2[CHUNK];  // global positions
    int tid = threadIdx.x;
    int e0 = blockIdx.x * CHUNK;
    int csize = nE - e0; if (csize > CHUNK) csize = CHUNK;

    for (int i = tid; i < NB; i += 256) h[i] = 0;
    __syncthreads();

    int es[EPT], ed[EPT];
    #pragma unroll
    for (int t = 0; t < EPT; ++t) {
        int e = e0 + t * 256 + tid;
        if (e < nE) {
            es[t] = src[e]; ed[t] = dst[e];
            atomicAdd(&h[ed[t] >> 6], 1u);
        } else { es[t] = -1; ed[t] = 0; }
    }
    __syncthreads();

    // block scan of h -> hloc (exclusive)
    unsigned loc[8]; unsigned s = 0;
    #pragma unroll
    for (int k = 0; k < 8; ++k) {
        int idx = tid * 8 + k;
        unsigned v = (idx < NB) ? h[idx] : 0u;
        loc[k] = s; s += v;
    }
    sc[tid] = s; __syncthreads();
    for (int off = 1; off < 256; off <<= 1) {
        unsigned a = (tid >= off) ? sc[tid - off] : 0u;
        __syncthreads(); sc[tid] += a; __syncthreads();
    }
    unsigned texcl = tid ? sc[tid - 1] : 0u;
    #pragma unroll
    for (int k = 0; k < 8; ++k) {
        int idx = tid * 8 + k;
        if (idx < NB) hloc[idx] = texcl + loc[k];
    }
    __syncthreads();

    // reserve global space per bucket
    for (int i = tid; i < NB; i += 256) {
        unsigned c = h[i];
        hbase[i] = c ? atomicAdd(&gcur[i], c) : 0u;
    }
    __syncthreads();
    for (int i = tid; i < NB; i += 256) h[i] = 0;   // reuse as local cursor
    __syncthreads();

    // place into LDS in bucket-local order
    #pragma unroll
    for (int t = 0; t < EPT; ++t) {
        if (es[t] >= 0) {
            int b = ed[t] >> 6;
            unsigned r = atomicAdd(&h[b], 1u);
            unsigned slot = hloc[b] + r;
            buf[slot] = (unsigned)es[t] | ((unsigned)(ed[t] & 63) << 17);
            buf2[slot] = hbase[b] + r;
        }
    }
    __syncthreads();

    // stream out (coalesced within bucket runs)
    for (int k = tid; k < csize; k += 256)
        pairs[buf2[k]] = buf[k];
}

// ---------------- aggregation: one block per 64-node bucket ----------------
// 512 threads = 8 waves. Wave = 4 lane-groups x 16 lanes; each group gathers one
// edge's 256B row as float4 (one dwordx4 per 4 edges). 4-deep independent unroll.
template<bool LAST>
__global__ __launch_bounds__(512) void agg_kernel(const unsigned* __restrict__ pairs,
                                                  const unsigned* __restrict__ gbase,
                                                  const unsigned* __restrict__ ghist,
                                                  const float* __restrict__ hs,
                                                  float* __restrict__ out) {
    __shared__ float acc[BSZ + 1][68];   // row BSZ = trash row; stride 68 spreads banks
    __shared__ unsigned cnt[BSZ];
    int tid = threadIdx.x;
    int b = blockIdx.x;
    int wave = tid >> 6, lane = tid & 63;
    int lg = lane >> 4;          // lane group 0..3 (edge within quad)
    int lx = lane & 15;          // position within group (feature quad)

    for (int i = tid; i < (BSZ + 1) * 68; i += 512) ((float*)acc)[i] = 0.f;
    if (tid < BSZ) cnt[tid] = 0;
    __syncthreads();

    unsigned start = gbase[b];
    int n = (int)ghist[b];
    const unsigned DUMMY = (unsigned)BSZ << 17;   // src=0 (safe), row BSZ (trash)
    for (int base = wave * 64; base < n; base += 512) {
        unsigned p = DUMMY;
        if (base + lane < n) {
            p = pairs[start + base + lane];
            atomicAdd(&cnt[p >> 17], 1u);    // in-degree (real edges only)
        }
        #pragma unroll
        for (int s4 = 0; s4 < 4; ++s4) {
            unsigned q[4]; float4 v[4];
            #pragma unroll
            for (int u = 0; u < 4; ++u) {
                q[u] = __shfl(p, s4 * 16 + u * 4 + lg);
                v[u] = *(const float4*)&hs[(size_t)(q[u] & 0x1FFFF) * FOUT + lx * 4];
            }
            #pragma unroll
            for (int u = 0; u < 4; ++u) {
                int dl = q[u] >> 17;
                atomicAdd(&acc[dl][lx * 4 + 0], v[u].x);
                atomicAdd(&acc[dl][lx * 4 + 1], v[u].y);
                atomicAdd(&acc[dl][lx * 4 + 2], v[u].z);
                atomicAdd(&acc[dl][lx * 4 + 3], v[u].w);
            }
        }
    }
    __syncthreads();

    #pragma unroll
    for (int i = 0; i < 8; ++i) {
        int nl = wave * 8 + i;
        int node = b * BSZ + nl;
        if (node < NN) {
            unsigned c = cnt[nl]; if (c < 1u) c = 1u;
            float ndv = rsqrtf((float)c);
            size_t oi = (size_t)node * FOUT + lane;
            float r = out[oi] + acc[nl][lane] * ndv;
            out[oi] = LAST ? tanhf(r) : r;
        }
    }
}

extern "C" void kernel_launch(void* const* d_in, const int* in_sizes, int n_in,
                              void* d_out, int out_size, void* d_ws, size_t ws_size,
                              hipStream_t stream) {
    const float* x = (const float*)d_in[0];
    const float* W = (const float*)d_in[1];
    const int* ei = (const int*)d_in[2];
    float* out = (float*)d_out;

    char* ws = (char*)d_ws;
    size_t o = 0;
    float* hs = (float*)(ws + o);           o += (size_t)NN * FOUT * 4;       // 25.6 MB
    unsigned* pairs = (unsigned*)(ws + o);  o += (size_t)EPR * 4;             // 6.4 MB
    unsigned* deg_s_all = (unsigned*)(ws + o); o += (size_t)4 * NN * 4;       // 1.6 MB
    unsigned* ghist_all = (unsigned*)(ws + o); o += (size_t)4 * NB * 4;       // contiguous w/ deg for memset
    float* ns_all = (float*)(ws + o);       o += (size_t)4 * NN * 4;          // 1.6 MB
    unsigned* gbase = (unsigned*)(ws + o);  o += (size_t)NB * 4;
    unsigned* gcur = (unsigned*)(ws + o);   o += (size_t)NB * 4;

    hipMemsetAsync(deg_s_all, 0, (size_t)(4 * NN + 4 * NB) * 4, stream);
    hipMemsetAsync(d_out, 0, (size_t)out_size * sizeof(float), stream);

    deg_all_kernel<<<2048, 256, 0, stream>>>(ei, deg_s_all, ghist_all);
    norm_all_kernel<<<(4 * NN + 255) / 256, 256, 0, stream>>>(deg_s_all, ns_all);

    for (int r = 0; r < 4; ++r) {
        const int* src = ei + (size_t)r * 2 * EPR;
        const int* dst = src + EPR;
        const float* w = W + (size_t)r * FIN * FOUT;

        gemm_kernel<<<(NN + BM - 1) / BM, 256, 0, stream>>>(x, w, hs, ns_all + (size_t)r * NN);
        scan_nb_kernel<<<1, 256, 0, stream>>>(ghist_all + (size_t)r * NB, gbase, gcur);
        part_kernel<<<(EPR + CHUNK - 1) / CHUNK, 256, 0, stream>>>(src, dst, gcur, pairs, EPR);
        if (r == 3)
            agg_kernel<true><<<NB, 512, 0, stream>>>(pairs, gbase, ghist_all + (size_t)r * NB, hs, out);
        else
            agg_kernel<false><<<NB, 512, 0, stream>>>(pairs, gbase, ghist_all + (size_t)r * NB, hs, out);
    }
}

// Round 6
// 3302.563 us; speedup vs baseline: 1.1884x; 1.0127x over previous
//
#include <hip/hip_runtime.h>
#include <hip/hip_bf16.h>

#define NN 100000
#define EPR 1600000
#define FIN 256
#define FOUT 64
#define BSZ 64            // dst nodes per bucket
#define NB 1563           // ceil(100000/64)
#define CHUNK 4096
#define EPT 16            // edges per thread in part_kernel

// ---------------- fused: out-degree + in-degree counting ----------------
__global__ void deg_all_kernel(const int* __restrict__ ei,
                               unsigned* __restrict__ deg_s_all,
                               unsigned* __restrict__ deg_d_all) {
    int i = blockIdx.x * blockDim.x + threadIdx.x;
    int stride = gridDim.x * blockDim.x;
    for (int e = i; e < EPR; e += stride) {
        #pragma unroll
        for (int r = 0; r < 4; ++r) {
            int s = ei[(size_t)r * 2 * EPR + e];
            int d = ei[(size_t)r * 2 * EPR + EPR + e];
            atomicAdd(&deg_s_all[r * NN + s], 1u);
            atomicAdd(&deg_d_all[r * NN + d], 1u);
        }
    }
}

// ---------------- bucket histogram = sum of 64 in-degrees ----------------
__global__ void ghist_kernel(const unsigned* __restrict__ deg_d_all,
                             unsigned* __restrict__ ghist_all) {
    int i = blockIdx.x * blockDim.x + threadIdx.x;   // 0 .. 4*NB-1
    if (i >= 4 * NB) return;
    int r = i / NB, b = i % NB;
    unsigned s = 0;
    int base = b * BSZ;
    #pragma unroll 8
    for (int j = 0; j < BSZ; ++j) {
        int node = base + j;
        if (node < NN) s += deg_d_all[r * NN + node];
    }
    ghist_all[i] = s;
}

// ---------------- degrees -> rsqrt norms (both s and d, 8*NN) ----------------
__global__ void norm_all_kernel(const unsigned* __restrict__ deg_all,
                                float* __restrict__ norm_all) {
    int i = blockIdx.x * blockDim.x + threadIdx.x;
    if (i < 8 * NN) {
        unsigned a = deg_all[i]; if (a < 1u) a = 1u;
        norm_all[i] = rsqrtf((float)a);
    }
}

// ---------------- fp32 GEMM: hs[N,64] = (x[N,256] @ w[256,64]) * ns[row] ----------------
#define BM 128
#define BK 32
__global__ __launch_bounds__(256) void gemm_kernel(const float* __restrict__ x,
                                                   const float* __restrict__ w,
                                                   float* __restrict__ hs,
                                                   const float* __restrict__ ns) {
    __shared__ float xs[BK][BM];
    __shared__ float wsh[BK][FOUT];
    int tid = threadIdx.x;
    int m0 = blockIdx.x * BM;
    int tc = tid & 7;
    int tr = tid >> 3;
    float acc[4][8];
    #pragma unroll
    for (int i = 0; i < 4; i++)
        #pragma unroll
        for (int j = 0; j < 8; j++) acc[i][j] = 0.f;

    for (int k0 = 0; k0 < FIN; k0 += BK) {
        #pragma unroll
        for (int t = 0; t < 4; ++t) {
            int f = tid * 4 + t;
            int row = f >> 3;
            int kp = (f & 7) << 2;
            int gr = m0 + row;
            const float4 v = *(const float4*)&x[(size_t)(gr < NN ? gr : 0) * FIN + k0 + kp];
            xs[kp + 0][row] = v.x;
            xs[kp + 1][row] = v.y;
            xs[kp + 2][row] = v.z;
            xs[kp + 3][row] = v.w;
        }
        #pragma unroll
        for (int t = 0; t < 2; ++t) {
            int f = tid * 2 + t;
            int kk = f >> 4;
            int c = (f & 15) << 2;
            *(float4*)&wsh[kk][c] = *(const float4*)&w[(size_t)(k0 + kk) * FOUT + c];
        }
        __syncthreads();
        #pragma unroll
        for (int k = 0; k < BK; ++k) {
            float4 xv = *(const float4*)&xs[k][tr * 4];
            float4 w0 = *(const float4*)&wsh[k][tc * 8];
            float4 w1 = *(const float4*)&wsh[k][tc * 8 + 4];
            float xa[4] = {xv.x, xv.y, xv.z, xv.w};
            float wb[8] = {w0.x, w0.y, w0.z, w0.w, w1.x, w1.y, w1.z, w1.w};
            #pragma unroll
            for (int i = 0; i < 4; i++)
                #pragma unroll
                for (int j = 0; j < 8; j++)
                    acc[i][j] = fmaf(xa[i], wb[j], acc[i][j]);
        }
        __syncthreads();
    }
    #pragma unroll
    for (int i = 0; i < 4; i++) {
        int gr = m0 + tr * 4 + i;
        if (gr < NN) {
            float sc = ns[gr];
            float4 o0 = {acc[i][0] * sc, acc[i][1] * sc, acc[i][2] * sc, acc[i][3] * sc};
            float4 o1 = {acc[i][4] * sc, acc[i][5] * sc, acc[i][6] * sc, acc[i][7] * sc};
            *(float4*)&hs[(size_t)gr * FOUT + tc * 8] = o0;
            *(float4*)&hs[(size_t)gr * FOUT + tc * 8 + 4] = o1;
        }
    }
}

// ---------------- exclusive scan of the NB bucket counts (one block) ----------------
__global__ void scan_nb_kernel(const unsigned* __restrict__ ghist,
                               unsigned* __restrict__ gbase, unsigned* __restrict__ gcur) {
    __shared__ unsigned sc[256];
    int tid = threadIdx.x;
    unsigned loc[8]; unsigned s = 0;
    #pragma unroll
    for (int k = 0; k < 8; ++k) {
        int idx = tid * 8 + k;
        unsigned v = (idx < NB) ? ghist[idx] : 0u;
        loc[k] = s; s += v;
    }
    sc[tid] = s; __syncthreads();
    for (int off = 1; off < 256; off <<= 1) {
        unsigned a = (tid >= off) ? sc[tid - off] : 0u;
        __syncthreads(); sc[tid] += a; __syncthreads();
    }
    unsigned texcl = tid ? sc[tid - 1] : 0u;
    #pragma unroll
    for (int k = 0; k < 8; ++k) {
        int idx = tid * 8 + k;
        if (idx < NB) { gbase[idx] = texcl + loc[k]; gcur[idx] = texcl + loc[k]; }
    }
}

// ---------------- partition: bucket edges by dst>>6, coalesced packed output ----------------
__global__ __launch_bounds__(256) void part_kernel(const int* __restrict__ src,
                                                   const int* __restrict__ dst,
                                                   unsigned* __restrict__ gcur,
                                                   unsigned* __restrict__ pairs, int nE) {
    __shared__ unsigned h[NB];      // histogram, then reused as local cursor
    __shared__ unsigned hloc[NB];   // exclusive scan (local slot base)
    __shared__ unsigned hbase[NB];  // reserved global base
    __shared__ unsigned sc[256];
    __shared__ unsigned buf[CHUNK];   // packed records in bucket-local order
    __shared__ unsigned buf2[CHUNK];  // global positions
    int tid = threadIdx.x;
    int e0 = blockIdx.x * CHUNK;
    int csize = nE - e0; if (csize > CHUNK) csize = CHUNK;

    for (int i = tid; i < NB; i += 256) h[i] = 0;
    __syncthreads();

    int es[EPT], ed[EPT];
    #pragma unroll
    for (int t = 0; t < EPT; ++t) {
        int e = e0 + t * 256 + tid;
        if (e < nE) {
            es[t] = src[e]; ed[t] = dst[e];
            atomicAdd(&h[ed[t] >> 6], 1u);
        } else { es[t] = -1; ed[t] = 0; }
    }
    __syncthreads();

    // block scan of h -> hloc (exclusive)
    unsigned loc[8]; unsigned s = 0;
    #pragma unroll
    for (int k = 0; k < 8; ++k) {
        int idx = tid * 8 + k;
        unsigned v = (idx < NB) ? h[idx] : 0u;
        loc[k] = s; s += v;
    }
    sc[tid] = s; __syncthreads();
    for (int off = 1; off < 256; off <<= 1) {
        unsigned a = (tid >= off) ? sc[tid - off] : 0u;
        __syncthreads(); sc[tid] += a; __syncthreads();
    }
    unsigned texcl = tid ? sc[tid - 1] : 0u;
    #pragma unroll
    for (int k = 0; k < 8; ++k) {
        int idx = tid * 8 + k;
        if (idx < NB) hloc[idx] = texcl + loc[k];
    }
    __syncthreads();

    // reserve global space per bucket
    for (int i = tid; i < NB; i += 256) {
        unsigned c = h[i];
        hbase[i] = c ? atomicAdd(&gcur[i], c) : 0u;
    }
    __syncthreads();
    for (int i = tid; i < NB; i += 256) h[i] = 0;   // reuse as local cursor
    __syncthreads();

    // place into LDS in bucket-local order
    #pragma unroll
    for (int t = 0; t < EPT; ++t) {
        if (es[t] >= 0) {
            int b = ed[t] >> 6;
            unsigned r = atomicAdd(&h[b], 1u);
            unsigned slot = hloc[b] + r;
            buf[slot] = (unsigned)es[t] | ((unsigned)(ed[t] & 63) << 17);
            buf2[slot] = hbase[b] + r;
        }
    }
    __syncthreads();

    // stream out (coalesced within bucket runs)
    for (int k = tid; k < csize; k += 256)
        pairs[buf2[k]] = buf[k];
}

// ---------------- aggregation: one block per 64-node bucket ----------------
// 512 threads = 8 waves. Wave = 4 lane-groups x 16 lanes. NO cross-lane ops:
// each group broadcast-loads its edge record straight from pairs[] (addr is a
// function of the loop counter only), all 16 records staged in registers, then
// gathers issued in batches of 4 float4 so >=4 are in flight per wave.
template<bool LAST>
__global__ __launch_bounds__(512, 2) void agg_kernel(const unsigned* __restrict__ pairs,
                                                     const unsigned* __restrict__ gbase,
                                                     const unsigned* __restrict__ ghist,
                                                     const float* __restrict__ hs,
                                                     const float* __restrict__ nd,
                                                     float* __restrict__ out) {
    __shared__ float acc[BSZ + 1][68];   // row BSZ = trash row; stride 68 spreads banks
    int tid = threadIdx.x;
    int b = blockIdx.x;
    int wave = tid >> 6, lane = tid & 63;
    int lg = lane >> 4;          // lane group 0..3 (edge within quad)
    int lx = lane & 15;          // position within group (feature quad)

    for (int i = tid; i < (BSZ + 1) * 68; i += 512) ((float*)acc)[i] = 0.f;
    __syncthreads();

    unsigned start = gbase[b];
    int n = (int)ghist[b];
    const unsigned DUMMY = (unsigned)BSZ << 17;   // src=0 (safe), row BSZ (trash)

    for (int base = wave * 64; base < n; base += 512) {
        // stage 16 records (64 edges / 4 groups); independent broadcast loads
        unsigned rec[16];
        #pragma unroll
        for (int u = 0; u < 16; ++u) {
            int k = base + u * 4 + lg;
            int idx = (k < n) ? k : (n - 1);
            unsigned rr = pairs[start + idx];
            rec[u] = (k < n) ? rr : DUMMY;
        }
        // gather + LDS accumulate, 4 float4 loads in flight per batch
        #pragma unroll
        for (int g = 0; g < 4; ++g) {
            float4 v[4];
            #pragma unroll
            for (int u2 = 0; u2 < 4; ++u2) {
                unsigned rr = rec[g * 4 + u2];
                v[u2] = *(const float4*)&hs[(size_t)(rr & 0x1FFFF) * FOUT + lx * 4];
            }
            #pragma unroll
            for (int u2 = 0; u2 < 4; ++u2) {
                int dl = rec[g * 4 + u2] >> 17;
                float* a = &acc[dl][lx * 4];
                atomicAdd(&a[0], v[u2].x);
                atomicAdd(&a[1], v[u2].y);
                atomicAdd(&a[2], v[u2].z);
                atomicAdd(&a[3], v[u2].w);
            }
        }
    }
    __syncthreads();

    #pragma unroll
    for (int i = 0; i < 8; ++i) {
        int nl = wave * 8 + i;
        int node = b * BSZ + nl;
        if (node < NN) {
            float ndv = nd[node];
            size_t oi = (size_t)node * FOUT + lane;
            float r = out[oi] + acc[nl][lane] * ndv;
            out[oi] = LAST ? tanhf(r) : r;
        }
    }
}

extern "C" void kernel_launch(void* const* d_in, const int* in_sizes, int n_in,
                              void* d_out, int out_size, void* d_ws, size_t ws_size,
                              hipStream_t stream) {
    const float* x = (const float*)d_in[0];
    const float* W = (const float*)d_in[1];
    const int* ei = (const int*)d_in[2];
    float* out = (float*)d_out;

    char* ws = (char*)d_ws;
    size_t o = 0;
    float* hs = (float*)(ws + o);           o += (size_t)NN * FOUT * 4;       // 25.6 MB
    unsigned* pairs = (unsigned*)(ws + o);  o += (size_t)EPR * 4;             // 6.4 MB
    unsigned* deg_all = (unsigned*)(ws + o); o += (size_t)8 * NN * 4;         // s(4NN) + d(4NN)
    unsigned* ghist_all = (unsigned*)(ws + o); o += (size_t)4 * NB * 4;       // contiguous w/ deg for memset
    float* norm_all = (float*)(ws + o);     o += (size_t)8 * NN * 4;          // ns(4NN) + nd(4NN)
    unsigned* gbase = (unsigned*)(ws + o);  o += (size_t)NB * 4;
    unsigned* gcur = (unsigned*)(ws + o);   o += (size_t)NB * 4;

    unsigned* deg_s_all = deg_all;
    unsigned* deg_d_all = deg_all + (size_t)4 * NN;
    float* ns_all = norm_all;
    float* nd_all = norm_all + (size_t)4 * NN;

    hipMemsetAsync(deg_all, 0, (size_t)(8 * NN + 4 * NB) * 4, stream);
    hipMemsetAsync(d_out, 0, (size_t)out_size * sizeof(float), stream);

    deg_all_kernel<<<2048, 256, 0, stream>>>(ei, deg_s_all, deg_d_all);
    ghist_kernel<<<(4 * NB + 255) / 256, 256, 0, stream>>>(deg_d_all, ghist_all);
    norm_all_kernel<<<(8 * NN + 255) / 256, 256, 0, stream>>>(deg_all, norm_all);

    for (int r = 0; r < 4; ++r) {
        const int* src = ei + (size_t)r * 2 * EPR;
        const int* dst = src + EPR;
        const float* w = W + (size_t)r * FIN * FOUT;

        gemm_kernel<<<(NN + BM - 1) / BM, 256, 0, stream>>>(x, w, hs, ns_all + (size_t)r * NN);
        scan_nb_kernel<<<1, 256, 0, stream>>>(ghist_all + (size_t)r * NB, gbase, gcur);
        part_kernel<<<(EPR + CHUNK - 1) / CHUNK, 256, 0, stream>>>(src, dst, gcur, pairs, EPR);
        if (r == 3)
            agg_kernel<true><<<NB, 512, 0, stream>>>(pairs, gbase, ghist_all + (size_t)r * NB,
                                                     hs, nd_all + (size_t)r * NN, out);
        else
            agg_kernel<false><<<NB, 512, 0, stream>>>(pairs, gbase, ghist_all + (size_t)r * NB,
                                                      hs, nd_all + (size_t)r * NN, out);
    }
}

// Round 7
// 3190.761 us; speedup vs baseline: 1.2300x; 1.0350x over previous
//
#include <hip/hip_runtime.h>
#include <hip/hip_bf16.h>

#define NN 100000
#define EPR 1600000
#define FIN 256
#define FOUT 64
#define BSZ 64            // dst nodes per bucket
#define NB 1563           // ceil(100000/64)
#define CHUNK 4096
#define EPT 16            // edges per thread in part_kernel

// ---------------- fused: out-degree + in-degree counting ----------------
__global__ void deg_all_kernel(const int* __restrict__ ei,
                               unsigned* __restrict__ deg_s_all,
                               unsigned* __restrict__ deg_d_all) {
    int i = blockIdx.x * blockDim.x + threadIdx.x;
    int stride = gridDim.x * blockDim.x;
    for (int e = i; e < EPR; e += stride) {
        #pragma unroll
        for (int r = 0; r < 4; ++r) {
            int s = ei[(size_t)r * 2 * EPR + e];
            int d = ei[(size_t)r * 2 * EPR + EPR + e];
            atomicAdd(&deg_s_all[r * NN + s], 1u);
            atomicAdd(&deg_d_all[r * NN + d], 1u);
        }
    }
}

// ---------------- bucket histogram = sum of 64 in-degrees ----------------
__global__ void ghist_kernel(const unsigned* __restrict__ deg_d_all,
                             unsigned* __restrict__ ghist_all) {
    int i = blockIdx.x * blockDim.x + threadIdx.x;   // 0 .. 4*NB-1
    if (i >= 4 * NB) return;
    int r = i / NB, b = i % NB;
    unsigned s = 0;
    int base = b * BSZ;
    #pragma unroll 8
    for (int j = 0; j < BSZ; ++j) {
        int node = base + j;
        if (node < NN) s += deg_d_all[r * NN + node];
    }
    ghist_all[i] = s;
}

// ---------------- degrees -> rsqrt norms (both s and d, 8*NN) ----------------
__global__ void norm_all_kernel(const unsigned* __restrict__ deg_all,
                                float* __restrict__ norm_all) {
    int i = blockIdx.x * blockDim.x + threadIdx.x;
    if (i < 8 * NN) {
        unsigned a = deg_all[i]; if (a < 1u) a = 1u;
        norm_all[i] = rsqrtf((float)a);
    }
}

// ---------------- fp32 GEMM: hs[N,64] = (x[N,256] @ w[256,64]) * ns[row] ----------------
#define BM 128
#define BK 32
__global__ __launch_bounds__(256) void gemm_kernel(const float* __restrict__ x,
                                                   const float* __restrict__ w,
                                                   float* __restrict__ hs,
                                                   const float* __restrict__ ns) {
    __shared__ float xs[BK][BM];
    __shared__ float wsh[BK][FOUT];
    int tid = threadIdx.x;
    int m0 = blockIdx.x * BM;
    int tc = tid & 7;
    int tr = tid >> 3;
    float acc[4][8];
    #pragma unroll
    for (int i = 0; i < 4; i++)
        #pragma unroll
        for (int j = 0; j < 8; j++) acc[i][j] = 0.f;

    for (int k0 = 0; k0 < FIN; k0 += BK) {
        #pragma unroll
        for (int t = 0; t < 4; ++t) {
            int f = tid * 4 + t;
            int row = f >> 3;
            int kp = (f & 7) << 2;
            int gr = m0 + row;
            const float4 v = *(const float4*)&x[(size_t)(gr < NN ? gr : 0) * FIN + k0 + kp];
            xs[kp + 0][row] = v.x;
            xs[kp + 1][row] = v.y;
            xs[kp + 2][row] = v.z;
            xs[kp + 3][row] = v.w;
        }
        #pragma unroll
        for (int t = 0; t < 2; ++t) {
            int f = tid * 2 + t;
            int kk = f >> 4;
            int c = (f & 15) << 2;
            *(float4*)&wsh[kk][c] = *(const float4*)&w[(size_t)(k0 + kk) * FOUT + c];
        }
        __syncthreads();
        #pragma unroll
        for (int k = 0; k < BK; ++k) {
            float4 xv = *(const float4*)&xs[k][tr * 4];
            float4 w0 = *(const float4*)&wsh[k][tc * 8];
            float4 w1 = *(const float4*)&wsh[k][tc * 8 + 4];
            float xa[4] = {xv.x, xv.y, xv.z, xv.w};
            float wb[8] = {w0.x, w0.y, w0.z, w0.w, w1.x, w1.y, w1.z, w1.w};
            #pragma unroll
            for (int i = 0; i < 4; i++)
                #pragma unroll
                for (int j = 0; j < 8; j++)
                    acc[i][j] = fmaf(xa[i], wb[j], acc[i][j]);
        }
        __syncthreads();
    }
    #pragma unroll
    for (int i = 0; i < 4; i++) {
        int gr = m0 + tr * 4 + i;
        if (gr < NN) {
            float sc = ns[gr];
            float4 o0 = {acc[i][0] * sc, acc[i][1] * sc, acc[i][2] * sc, acc[i][3] * sc};
            float4 o1 = {acc[i][4] * sc, acc[i][5] * sc, acc[i][6] * sc, acc[i][7] * sc};
            *(float4*)&hs[(size_t)gr * FOUT + tc * 8] = o0;
            *(float4*)&hs[(size_t)gr * FOUT + tc * 8 + 4] = o1;
        }
    }
}

// ---------------- exclusive scan of the NB bucket counts (one block) ----------------
__global__ void scan_nb_kernel(const unsigned* __restrict__ ghist,
                               unsigned* __restrict__ gbase, unsigned* __restrict__ gcur) {
    __shared__ unsigned sc[256];
    int tid = threadIdx.x;
    unsigned loc[8]; unsigned s = 0;
    #pragma unroll
    for (int k = 0; k < 8; ++k) {
        int idx = tid * 8 + k;
        unsigned v = (idx < NB) ? ghist[idx] : 0u;
        loc[k] = s; s += v;
    }
    sc[tid] = s; __syncthreads();
    for (int off = 1; off < 256; off <<= 1) {
        unsigned a = (tid >= off) ? sc[tid - off] : 0u;
        __syncthreads(); sc[tid] += a; __syncthreads();
    }
    unsigned texcl = tid ? sc[tid - 1] : 0u;
    #pragma unroll
    for (int k = 0; k < 8; ++k) {
        int idx = tid * 8 + k;
        if (idx < NB) { gbase[idx] = texcl + loc[k]; gcur[idx] = texcl + loc[k]; }
    }
}

// ---------------- partition: bucket edges by dst>>6, coalesced packed output ----------------
__global__ __launch_bounds__(256) void part_kernel(const int* __restrict__ src,
                                                   const int* __restrict__ dst,
                                                   unsigned* __restrict__ gcur,
                                                   unsigned* __restrict__ pairs, int nE) {
    __shared__ unsigned h[NB];      // histogram, then reused as local cursor
    __shared__ unsigned hloc[NB];   // exclusive scan (local slot base)
    __shared__ unsigned hbase[NB];  // reserved global base
    __shared__ unsigned sc[256];
    __shared__ unsigned buf[CHUNK];   // packed records in bucket-local order
    __shared__ unsigned buf2[CHUNK];  // global positions
    int tid = threadIdx.x;
    int e0 = blockIdx.x * CHUNK;
    int csize = nE - e0; if (csize > CHUNK) csize = CHUNK;

    for (int i = tid; i < NB; i += 256) h[i] = 0;
    __syncthreads();

    int es[EPT], ed[EPT];
    #pragma unroll
    for (int t = 0; t < EPT; ++t) {
        int e = e0 + t * 256 + tid;
        if (e < nE) {
            es[t] = src[e]; ed[t] = dst[e];
            atomicAdd(&h[ed[t] >> 6], 1u);
        } else { es[t] = -1; ed[t] = 0; }
    }
    __syncthreads();

    // block scan of h -> hloc (exclusive)
    unsigned loc[8]; unsigned s = 0;
    #pragma unroll
    for (int k = 0; k < 8; ++k) {
        int idx = tid * 8 + k;
        unsigned v = (idx < NB) ? h[idx] : 0u;
        loc[k] = s; s += v;
    }
    sc[tid] = s; __syncthreads();
    for (int off = 1; off < 256; off <<= 1) {
        unsigned a = (tid >= off) ? sc[tid - off] : 0u;
        __syncthreads(); sc[tid] += a; __syncthreads();
    }
    unsigned texcl = tid ? sc[tid - 1] : 0u;
    #pragma unroll
    for (int k = 0; k < 8; ++k) {
        int idx = tid * 8 + k;
        if (idx < NB) hloc[idx] = texcl + loc[k];
    }
    __syncthreads();

    // reserve global space per bucket
    for (int i = tid; i < NB; i += 256) {
        unsigned c = h[i];
        hbase[i] = c ? atomicAdd(&gcur[i], c) : 0u;
    }
    __syncthreads();
    for (int i = tid; i < NB; i += 256) h[i] = 0;   // reuse as local cursor
    __syncthreads();

    // place into LDS in bucket-local order
    #pragma unroll
    for (int t = 0; t < EPT; ++t) {
        if (es[t] >= 0) {
            int b = ed[t] >> 6;
            unsigned r = atomicAdd(&h[b], 1u);
            unsigned slot = hloc[b] + r;
            buf[slot] = (unsigned)es[t] | ((unsigned)(ed[t] & 63) << 17);
            buf2[slot] = hbase[b] + r;
        }
    }
    __syncthreads();

    // stream out (coalesced within bucket runs)
    for (int k = tid; k < csize; k += 256)
        pairs[buf2[k]] = buf[k];
}

// ---------------- aggregation: one block per 64-node bucket ----------------
// 1024 threads = 16 waves; WAVE-PER-EDGE (lane = feature). Per edge: broadcast
// record load -> one coalesced 256B row gather -> ds_add. 2 blocks/CU = 32
// waves/CU (HW max); latency hidden by wave count, 2 edges in flight per wave.
template<bool LAST>
__global__ __launch_bounds__(1024, 8) void agg_kernel(const unsigned* __restrict__ pairs,
                                                      const unsigned* __restrict__ gbase,
                                                      const unsigned* __restrict__ ghist,
                                                      const float* __restrict__ hs,
                                                      const float* __restrict__ nd,
                                                      float* __restrict__ out) {
    __shared__ float acc[BSZ][68];   // stride 68: 64-lane row access = 2-way (free)
    int tid = threadIdx.x;
    int b = blockIdx.x;
    int wave = tid >> 6, lane = tid & 63;   // 16 waves

    for (int i = tid; i < BSZ * 68; i += 1024) ((float*)acc)[i] = 0.f;
    __syncthreads();

    unsigned start = gbase[b];
    int n = (int)ghist[b];

    // software pipeline: records for edges (idx, idx+16) prefetched one iter ahead
    int idx = wave;
    unsigned ra = (idx < n) ? pairs[start + idx] : 0u;
    unsigned rb = (idx + 16 < n) ? pairs[start + idx + 16] : 0u;
    while (idx < n) {
        bool hb = (idx + 16) < n;
        // issue both gathers (independent 256B coalesced loads)
        float va = hs[(size_t)(ra & 0x1FFFF) * FOUT + lane];
        float vb = hb ? hs[(size_t)(rb & 0x1FFFF) * FOUT + lane] : 0.f;
        // prefetch next pair of records
        int idx2 = idx + 32;
        unsigned ra2 = (idx2 < n) ? pairs[start + idx2] : 0u;
        unsigned rb2 = (idx2 + 16 < n) ? pairs[start + idx2 + 16] : 0u;
        // accumulate
        atomicAdd(&acc[ra >> 17][lane], va);
        if (hb) atomicAdd(&acc[rb >> 17][lane], vb);
        ra = ra2; rb = rb2; idx = idx2;
    }
    __syncthreads();

    #pragma unroll
    for (int i = 0; i < 4; ++i) {
        int nl = wave * 4 + i;
        int node = b * BSZ + nl;
        if (node < NN) {
            float ndv = nd[node];
            size_t oi = (size_t)node * FOUT + lane;
            float r = out[oi] + acc[nl][lane] * ndv;
            out[oi] = LAST ? tanhf(r) : r;
        }
    }
}

extern "C" void kernel_launch(void* const* d_in, const int* in_sizes, int n_in,
                              void* d_out, int out_size, void* d_ws, size_t ws_size,
                              hipStream_t stream) {
    const float* x = (const float*)d_in[0];
    const float* W = (const float*)d_in[1];
    const int* ei = (const int*)d_in[2];
    float* out = (float*)d_out;

    char* ws = (char*)d_ws;
    size_t o = 0;
    float* hs = (float*)(ws + o);           o += (size_t)NN * FOUT * 4;       // 25.6 MB
    unsigned* pairs = (unsigned*)(ws + o);  o += (size_t)EPR * 4;             // 6.4 MB
    unsigned* deg_all = (unsigned*)(ws + o); o += (size_t)8 * NN * 4;         // s(4NN) + d(4NN)
    unsigned* ghist_all = (unsigned*)(ws + o); o += (size_t)4 * NB * 4;       // contiguous w/ deg for memset
    float* norm_all = (float*)(ws + o);     o += (size_t)8 * NN * 4;          // ns(4NN) + nd(4NN)
    unsigned* gbase = (unsigned*)(ws + o);  o += (size_t)NB * 4;
    unsigned* gcur = (unsigned*)(ws + o);   o += (size_t)NB * 4;

    unsigned* deg_s_all = deg_all;
    unsigned* deg_d_all = deg_all + (size_t)4 * NN;
    float* ns_all = norm_all;
    float* nd_all = norm_all + (size_t)4 * NN;

    hipMemsetAsync(deg_all, 0, (size_t)(8 * NN + 4 * NB) * 4, stream);
    hipMemsetAsync(d_out, 0, (size_t)out_size * sizeof(float), stream);

    deg_all_kernel<<<2048, 256, 0, stream>>>(ei, deg_s_all, deg_d_all);
    ghist_kernel<<<(4 * NB + 255) / 256, 256, 0, stream>>>(deg_d_all, ghist_all);
    norm_all_kernel<<<(8 * NN + 255) / 256, 256, 0, stream>>>(deg_all, norm_all);

    for (int r = 0; r < 4; ++r) {
        const int* src = ei + (size_t)r * 2 * EPR;
        const int* dst = src + EPR;
        const float* w = W + (size_t)r * FIN * FOUT;

        gemm_kernel<<<(NN + BM - 1) / BM, 256, 0, stream>>>(x, w, hs, ns_all + (size_t)r * NN);
        scan_nb_kernel<<<1, 256, 0, stream>>>(ghist_all + (size_t)r * NB, gbase, gcur);
        part_kernel<<<(EPR + CHUNK - 1) / CHUNK, 256, 0, stream>>>(src, dst, gcur, pairs, EPR);
        if (r == 3)
            agg_kernel<true><<<NB, 1024, 0, stream>>>(pairs, gbase, ghist_all + (size_t)r * NB,
                                                      hs, nd_all + (size_t)r * NN, out);
        else
            agg_kernel<false><<<NB, 1024, 0, stream>>>(pairs, gbase, ghist_all + (size_t)r * NB,
                                                       hs, nd_all + (size_t)r * NN, out);
    }
}

// Round 8
// 1312.202 us; speedup vs baseline: 2.9909x; 2.4316x over previous
//
#include <hip/hip_runtime.h>
#include <hip/hip_bf16.h>

#define NN 100000
#define EPR 1600000
#define FIN 256
#define FOUT 64
#define BSZ 64            // dst nodes per bucket
#define NB 1563           // ceil(100000/64)
#define CHUNK 4096
#define EPT 16            // edges per thread in part_kernel
#define CAP 4096          // max edges per bucket handled by LDS sort (mean 1024, sd 32)

// ---------------- fused: out-degree + in-degree counting ----------------
__global__ void deg_all_kernel(const int* __restrict__ ei,
                               unsigned* __restrict__ deg_s_all,
                               unsigned* __restrict__ deg_d_all) {
    int i = blockIdx.x * blockDim.x + threadIdx.x;
    int stride = gridDim.x * blockDim.x;
    for (int e = i; e < EPR; e += stride) {
        #pragma unroll
        for (int r = 0; r < 4; ++r) {
            int s = ei[(size_t)r * 2 * EPR + e];
            int d = ei[(size_t)r * 2 * EPR + EPR + e];
            atomicAdd(&deg_s_all[r * NN + s], 1u);
            atomicAdd(&deg_d_all[r * NN + d], 1u);
        }
    }
}

// ---------------- bucket histogram = sum of 64 in-degrees ----------------
__global__ void ghist_kernel(const unsigned* __restrict__ deg_d_all,
                             unsigned* __restrict__ ghist_all) {
    int i = blockIdx.x * blockDim.x + threadIdx.x;   // 0 .. 4*NB-1
    if (i >= 4 * NB) return;
    int r = i / NB, b = i % NB;
    unsigned s = 0;
    int base = b * BSZ;
    #pragma unroll 8
    for (int j = 0; j < BSZ; ++j) {
        int node = base + j;
        if (node < NN) s += deg_d_all[r * NN + node];
    }
    ghist_all[i] = s;
}

// ---------------- degrees -> rsqrt norms ----------------
__global__ void norm_all_kernel(const unsigned* __restrict__ deg_all,
                                float* __restrict__ norm_all) {
    int i = blockIdx.x * blockDim.x + threadIdx.x;
    if (i < 8 * NN) {
        unsigned a = deg_all[i]; if (a < 1u) a = 1u;
        norm_all[i] = rsqrtf((float)a);
    }
}

// ---------------- fp32 GEMM: hs[N,64] = (x[N,256] @ w[256,64]) * ns[row] ----------------
#define BM 128
#define BK 32
__global__ __launch_bounds__(256) void gemm_kernel(const float* __restrict__ x,
                                                   const float* __restrict__ w,
                                                   float* __restrict__ hs,
                                                   const float* __restrict__ ns) {
    __shared__ float xs[BK][BM];
    __shared__ float wsh[BK][FOUT];
    int tid = threadIdx.x;
    int m0 = blockIdx.x * BM;
    int tc = tid & 7;
    int tr = tid >> 3;
    float acc[4][8];
    #pragma unroll
    for (int i = 0; i < 4; i++)
        #pragma unroll
        for (int j = 0; j < 8; j++) acc[i][j] = 0.f;

    for (int k0 = 0; k0 < FIN; k0 += BK) {
        #pragma unroll
        for (int t = 0; t < 4; ++t) {
            int f = tid * 4 + t;
            int row = f >> 3;
            int kp = (f & 7) << 2;
            int gr = m0 + row;
            const float4 v = *(const float4*)&x[(size_t)(gr < NN ? gr : 0) * FIN + k0 + kp];
            xs[kp + 0][row] = v.x;
            xs[kp + 1][row] = v.y;
            xs[kp + 2][row] = v.z;
            xs[kp + 3][row] = v.w;
        }
        #pragma unroll
        for (int t = 0; t < 2; ++t) {
            int f = tid * 2 + t;
            int kk = f >> 4;
            int c = (f & 15) << 2;
            *(float4*)&wsh[kk][c] = *(const float4*)&w[(size_t)(k0 + kk) * FOUT + c];
        }
        __syncthreads();
        #pragma unroll
        for (int k = 0; k < BK; ++k) {
            float4 xv = *(const float4*)&xs[k][tr * 4];
            float4 w0 = *(const float4*)&wsh[k][tc * 8];
            float4 w1 = *(const float4*)&wsh[k][tc * 8 + 4];
            float xa[4] = {xv.x, xv.y, xv.z, xv.w};
            float wb[8] = {w0.x, w0.y, w0.z, w0.w, w1.x, w1.y, w1.z, w1.w};
            #pragma unroll
            for (int i = 0; i < 4; i++)
                #pragma unroll
                for (int j = 0; j < 8; j++)
                    acc[i][j] = fmaf(xa[i], wb[j], acc[i][j]);
        }
        __syncthreads();
    }
    #pragma unroll
    for (int i = 0; i < 4; i++) {
        int gr = m0 + tr * 4 + i;
        if (gr < NN) {
            float sc = ns[gr];
            float4 o0 = {acc[i][0] * sc, acc[i][1] * sc, acc[i][2] * sc, acc[i][3] * sc};
            float4 o1 = {acc[i][4] * sc, acc[i][5] * sc, acc[i][6] * sc, acc[i][7] * sc};
            *(float4*)&hs[(size_t)gr * FOUT + tc * 8] = o0;
            *(float4*)&hs[(size_t)gr * FOUT + tc * 8 + 4] = o1;
        }
    }
}

// ---------------- exclusive scan of the NB bucket counts (one block) ----------------
__global__ void scan_nb_kernel(const unsigned* __restrict__ ghist,
                               unsigned* __restrict__ gbase, unsigned* __restrict__ gcur) {
    __shared__ unsigned sc[256];
    int tid = threadIdx.x;
    unsigned loc[8]; unsigned s = 0;
    #pragma unroll
    for (int k = 0; k < 8; ++k) {
        int idx = tid * 8 + k;
        unsigned v = (idx < NB) ? ghist[idx] : 0u;
        loc[k] = s; s += v;
    }
    sc[tid] = s; __syncthreads();
    for (int off = 1; off < 256; off <<= 1) {
        unsigned a = (tid >= off) ? sc[tid - off] : 0u;
        __syncthreads(); sc[tid] += a; __syncthreads();
    }
    unsigned texcl = tid ? sc[tid - 1] : 0u;
    #pragma unroll
    for (int k = 0; k < 8; ++k) {
        int idx = tid * 8 + k;
        if (idx < NB) { gbase[idx] = texcl + loc[k]; gcur[idx] = texcl + loc[k]; }
    }
}

// ---------------- partition: bucket edges by dst>>6, coalesced packed output ----------------
__global__ __launch_bounds__(256) void part_kernel(const int* __restrict__ src,
                                                   const int* __restrict__ dst,
                                                   unsigned* __restrict__ gcur,
                                                   unsigned* __restrict__ pairs, int nE) {
    __shared__ unsigned h[NB];      // histogram, then reused as local cursor
    __shared__ unsigned hloc[NB];   // exclusive scan (local slot base)
    __shared__ unsigned hbase[NB];  // reserved global base
    __shared__ unsigned sc[256];
    __shared__ unsigned buf[CHUNK];   // packed records in bucket-local order
    __shared__ unsigned buf2[CHUNK];  // global positions
    int tid = threadIdx.x;
    int e0 = blockIdx.x * CHUNK;
    int csize = nE - e0; if (csize > CHUNK) csize = CHUNK;

    for (int i = tid; i < NB; i += 256) h[i] = 0;
    __syncthreads();

    int es[EPT], ed[EPT];
    #pragma unroll
    for (int t = 0; t < EPT; ++t) {
        int e = e0 + t * 256 + tid;
        if (e < nE) {
            es[t] = src[e]; ed[t] = dst[e];
            atomicAdd(&h[ed[t] >> 6], 1u);
        } else { es[t] = -1; ed[t] = 0; }
    }
    __syncthreads();

    // block scan of h -> hloc (exclusive)
    unsigned loc[8]; unsigned s = 0;
    #pragma unroll
    for (int k = 0; k < 8; ++k) {
        int idx = tid * 8 + k;
        unsigned v = (idx < NB) ? h[idx] : 0u;
        loc[k] = s; s += v;
    }
    sc[tid] = s; __syncthreads();
    for (int off = 1; off < 256; off <<= 1) {
        unsigned a = (tid >= off) ? sc[tid - off] : 0u;
        __syncthreads(); sc[tid] += a; __syncthreads();
    }
    unsigned texcl = tid ? sc[tid - 1] : 0u;
    #pragma unroll
    for (int k = 0; k < 8; ++k) {
        int idx = tid * 8 + k;
        if (idx < NB) hloc[idx] = texcl + loc[k];
    }
    __syncthreads();

    // reserve global space per bucket
    for (int i = tid; i < NB; i += 256) {
        unsigned c = h[i];
        hbase[i] = c ? atomicAdd(&gcur[i], c) : 0u;
    }
    __syncthreads();
    for (int i = tid; i < NB; i += 256) h[i] = 0;   // reuse as local cursor
    __syncthreads();

    // place into LDS in bucket-local order
    #pragma unroll
    for (int t = 0; t < EPT; ++t) {
        if (es[t] >= 0) {
            int b = ed[t] >> 6;
            unsigned r = atomicAdd(&h[b], 1u);
            unsigned slot = hloc[b] + r;
            buf[slot] = (unsigned)es[t] | ((unsigned)(ed[t] & 63) << 17);
            buf2[slot] = hbase[b] + r;
        }
    }
    __syncthreads();

    // stream out (coalesced within bucket runs)
    for (int k = tid; k < csize; k += 256)
        pairs[buf2[k]] = buf[k];
}

// ---------------- fused sort+aggregate: one block per 64-node bucket ----------------
// 512 threads = 8 waves. Phase 1: counting-sort the bucket's records into LDS
// (all global accesses coalesced, sort via cheap u32 LDS atomics). Phase 2:
// wave w owns nodes w*8..w*8+7; per node, round-2-style shfl-broadcast gather
// with REGISTER accumulation (no LDS atomics, no vmcnt(0) serialization).
template<bool LAST>
__global__ __launch_bounds__(512, 8) void aggsort_kernel(const unsigned* __restrict__ pairs,
                                                         const unsigned* __restrict__ gbase,
                                                         const unsigned* __restrict__ ghist,
                                                         const float* __restrict__ hs,
                                                         float* __restrict__ out) {
    __shared__ unsigned sorted[CAP];
    __shared__ unsigned cnt[BSZ];       // histogram -> cursor
    __shared__ unsigned loff[BSZ + 1];  // exclusive offsets
    int tid = threadIdx.x;
    int b = blockIdx.x;
    int wave = tid >> 6, lane = tid & 63;

    unsigned start = gbase[b];
    int n = (int)ghist[b];

    if (n <= CAP) {
        if (tid < BSZ) cnt[tid] = 0;
        __syncthreads();
        unsigned rec[CAP / 512];
        #pragma unroll
        for (int t = 0; t < CAP / 512; ++t) {
            int i = t * 512 + tid;
            rec[t] = 0xFFFFFFFFu;
            if (i < n) {
                rec[t] = pairs[start + i];
                atomicAdd(&cnt[rec[t] >> 17], 1u);
            }
        }
        __syncthreads();
        if (wave == 0) {   // 64-wide exclusive scan of counters
            unsigned v = cnt[lane];
            unsigned sum = v;
            #pragma unroll
            for (int o = 1; o < 64; o <<= 1) {
                unsigned u = __shfl_up(sum, o);
                if (lane >= o) sum += u;
            }
            loff[lane + 1] = sum;
            if (lane == 0) loff[0] = 0;
            cnt[lane] = sum - v;   // exclusive base -> cursor
        }
        __syncthreads();
        #pragma unroll
        for (int t = 0; t < CAP / 512; ++t) {
            if (rec[t] != 0xFFFFFFFFu) {
                unsigned p = atomicAdd(&cnt[rec[t] >> 17], 1u);
                sorted[p] = rec[t];
            }
        }
        __syncthreads();

        for (int i = 0; i < 8; ++i) {
            int nl = wave * 8 + i;
            int node = b * BSZ + nl;
            if (node >= NN) break;
            int lo = (int)loff[nl], hi = (int)loff[nl + 1];
            float acc = 0.f;
            for (int base2 = lo; base2 < hi; base2 += 64) {
                int m = hi - base2; if (m > 64) m = 64;
                unsigned sl = (base2 + lane < hi) ? sorted[base2 + lane] : 0u;
                for (int j = 0; j < m; ++j) {
                    unsigned q = __shfl(sl, j);
                    acc += hs[(size_t)(q & 0x1FFFF) * FOUT + lane];
                }
            }
            int deg = hi - lo; if (deg < 1) deg = 1;
            float ndv = rsqrtf((float)deg);
            size_t oi = (size_t)node * FOUT + lane;
            float r = out[oi] + acc * ndv;
            out[oi] = LAST ? tanhf(r) : r;
        }
    } else {
        // overflow fallback (not expected for this input): scan-all per node
        for (int i = 0; i < 8; ++i) {
            int nl = wave * 8 + i;
            int node = b * BSZ + nl;
            if (node >= NN) break;
            float acc = 0.f; int deg = 0;
            for (int base2 = 0; base2 < n; base2 += 64) {
                int m = n - base2; if (m > 64) m = 64;
                unsigned sl = (base2 + lane < n) ? pairs[start + base2 + lane] : 0xFFFFFFFFu;
                for (int j = 0; j < m; ++j) {
                    unsigned q = __shfl(sl, j);
                    if ((int)(q >> 17) == nl) {
                        acc += hs[(size_t)(q & 0x1FFFF) * FOUT + lane];
                        ++deg;
                    }
                }
            }
            if (deg < 1) deg = 1;
            float ndv = rsqrtf((float)deg);
            size_t oi = (size_t)node * FOUT + lane;
            float r = out[oi] + acc * ndv;
            out[oi] = LAST ? tanhf(r) : r;
        }
    }
}

extern "C" void kernel_launch(void* const* d_in, const int* in_sizes, int n_in,
                              void* d_out, int out_size, void* d_ws, size_t ws_size,
                              hipStream_t stream) {
    const float* x = (const float*)d_in[0];
    const float* W = (const float*)d_in[1];
    const int* ei = (const int*)d_in[2];
    float* out = (float*)d_out;

    char* ws = (char*)d_ws;
    size_t o = 0;
    float* hs = (float*)(ws + o);           o += (size_t)NN * FOUT * 4;       // 25.6 MB
    unsigned* pairs = (unsigned*)(ws + o);  o += (size_t)EPR * 4;             // 6.4 MB
    unsigned* deg_all = (unsigned*)(ws + o); o += (size_t)8 * NN * 4;         // s(4NN) + d(4NN)
    unsigned* ghist_all = (unsigned*)(ws + o); o += (size_t)4 * NB * 4;       // contiguous w/ deg for memset
    float* norm_all = (float*)(ws + o);     o += (size_t)8 * NN * 4;          // ns(4NN) + nd(4NN)
    unsigned* gbase = (unsigned*)(ws + o);  o += (size_t)NB * 4;
    unsigned* gcur = (unsigned*)(ws + o);   o += (size_t)NB * 4;

    unsigned* deg_s_all = deg_all;
    unsigned* deg_d_all = deg_all + (size_t)4 * NN;
    float* ns_all = norm_all;

    hipMemsetAsync(deg_all, 0, (size_t)(8 * NN + 4 * NB) * 4, stream);
    hipMemsetAsync(d_out, 0, (size_t)out_size * sizeof(float), stream);

    deg_all_kernel<<<2048, 256, 0, stream>>>(ei, deg_s_all, deg_d_all);
    ghist_kernel<<<(4 * NB + 255) / 256, 256, 0, stream>>>(deg_d_all, ghist_all);
    norm_all_kernel<<<(8 * NN + 255) / 256, 256, 0, stream>>>(deg_all, norm_all);

    for (int r = 0; r < 4; ++r) {
        const int* src = ei + (size_t)r * 2 * EPR;
        const int* dst = src + EPR;
        const float* w = W + (size_t)r * FIN * FOUT;

        gemm_kernel<<<(NN + BM - 1) / BM, 256, 0, stream>>>(x, w, hs, ns_all + (size_t)r * NN);
        scan_nb_kernel<<<1, 256, 0, stream>>>(ghist_all + (size_t)r * NB, gbase, gcur);
        part_kernel<<<(EPR + CHUNK - 1) / CHUNK, 256, 0, stream>>>(src, dst, gcur, pairs, EPR);
        if (r == 3)
            aggsort_kernel<true><<<NB, 512, 0, stream>>>(pairs, gbase, ghist_all + (size_t)r * NB, hs, out);
        else
            aggsort_kernel<false><<<NB, 512, 0, stream>>>(pairs, gbase, ghist_all + (size_t)r * NB, hs, out);
    }
}

// Round 9
// 925.936 us; speedup vs baseline: 4.2385x; 1.4172x over previous
//
#include <hip/hip_runtime.h>
#include <hip/hip_bf16.h>

#define NN 100000
#define EPR 1600000
#define FIN 256
#define FOUT 64
#define BSZ 64            // nodes per bucket
#define NB 1563           // ceil(100000/64)
#define NBP 1568          // padded row stride for block-bucket tables
#define CHUNK 4096
#define NBLK 391          // ceil(EPR/CHUNK)
#define EPT 16            // edges per thread in hist/place
#define CAP 4096          // max edges per bucket for LDS sort (mean 1024, sd 32)

// ---------------- per-block bucket histograms (src & dst), no global atomics ----------------
__global__ __launch_bounds__(256) void hist_kernel(const int* __restrict__ src,
                                                   const int* __restrict__ dst,
                                                   unsigned* __restrict__ btabD,
                                                   unsigned* __restrict__ btabS, int nE) {
    __shared__ unsigned hD[NB], hS[NB];
    int tid = threadIdx.x;
    for (int i = tid; i < NB; i += 256) { hD[i] = 0; hS[i] = 0; }
    __syncthreads();
    int e0 = blockIdx.x * CHUNK;
    #pragma unroll
    for (int t = 0; t < EPT; ++t) {
        int e = e0 + t * 256 + tid;
        if (e < nE) {
            atomicAdd(&hS[src[e] >> 6], 1u);
            atomicAdd(&hD[dst[e] >> 6], 1u);
        }
    }
    __syncthreads();
    for (int i = tid; i < NB; i += 256) {
        btabD[(size_t)blockIdx.x * NBP + i] = hD[i];
        btabS[(size_t)blockIdx.x * NBP + i] = hS[i];
    }
}

// ---------------- per-bucket: exclusive scan over blocks (in place) + totals ----------------
__global__ __launch_bounds__(256) void btot_kernel(unsigned* __restrict__ btabD,
                                                   unsigned* __restrict__ btabS,
                                                   unsigned* __restrict__ totD,
                                                   unsigned* __restrict__ totS) {
    unsigned* tab = blockIdx.y ? btabS : btabD;
    unsigned* tot = blockIdx.y ? totS : totD;
    __shared__ unsigned tile[NBLK][8];
    int b0 = blockIdx.x * 8;
    for (int idx = threadIdx.x; idx < NBLK * 8; idx += 256) {
        int blk = idx >> 3, bb = idx & 7;
        int b = b0 + bb;
        tile[blk][bb] = (b < NB) ? tab[(size_t)blk * NBP + b] : 0u;
    }
    __syncthreads();
    if (threadIdx.x < 8) {
        int bb = threadIdx.x;
        unsigned s = 0;
        for (int blk = 0; blk < NBLK; ++blk) {
            unsigned v = tile[blk][bb];
            tile[blk][bb] = s;
            s += v;
        }
        if (b0 + bb < NB) tot[b0 + bb] = s;
    }
    __syncthreads();
    for (int idx = threadIdx.x; idx < NBLK * 8; idx += 256) {
        int blk = idx >> 3, bb = idx & 7;
        int b = b0 + bb;
        if (b < NB) tab[(size_t)blk * NBP + b] = tile[blk][bb];
    }
}

// ---------------- exclusive scan of bucket totals -> global bases (2 blocks: D,S) ----------------
__global__ void scan_nb2_kernel(const unsigned* __restrict__ totD, const unsigned* __restrict__ totS,
                                unsigned* __restrict__ gbaseD, unsigned* __restrict__ gbaseS) {
    const unsigned* tot = blockIdx.x ? totS : totD;
    unsigned* gb = blockIdx.x ? gbaseS : gbaseD;
    __shared__ unsigned sc[256];
    int tid = threadIdx.x;
    unsigned loc[8]; unsigned s = 0;
    #pragma unroll
    for (int k = 0; k < 8; ++k) {
        int idx = tid * 8 + k;
        unsigned v = (idx < NB) ? tot[idx] : 0u;
        loc[k] = s; s += v;
    }
    sc[tid] = s; __syncthreads();
    for (int off = 1; off < 256; off <<= 1) {
        unsigned a = (tid >= off) ? sc[tid - off] : 0u;
        __syncthreads(); sc[tid] += a; __syncthreads();
    }
    unsigned texcl = tid ? sc[tid - 1] : 0u;
    #pragma unroll
    for (int k = 0; k < 8; ++k) {
        int idx = tid * 8 + k;
        if (idx < NB) gb[idx] = texcl + loc[k];
    }
}

// ---------------- place edges into dst-bucketed order (deterministic, atomic-free global) ----------------
__global__ __launch_bounds__(256) void placeD_kernel(const int* __restrict__ src,
                                                     const int* __restrict__ dst,
                                                     const unsigned* __restrict__ gbase,
                                                     const unsigned* __restrict__ pblk,
                                                     unsigned* __restrict__ pairs, int nE) {
    __shared__ unsigned h[NB], hloc[NB], hbase[NB], sc[256];
    __shared__ unsigned buf[CHUNK], buf2[CHUNK];
    int tid = threadIdx.x, blk = blockIdx.x;
    int e0 = blk * CHUNK;
    int csize = nE - e0; if (csize > CHUNK) csize = CHUNK;

    for (int i = tid; i < NB; i += 256) h[i] = 0;
    __syncthreads();

    int es[EPT], ed[EPT];
    #pragma unroll
    for (int t = 0; t < EPT; ++t) {
        int e = e0 + t * 256 + tid;
        if (e < nE) { es[t] = src[e]; ed[t] = dst[e]; atomicAdd(&h[ed[t] >> 6], 1u); }
        else { es[t] = -1; ed[t] = 0; }
    }
    __syncthreads();

    unsigned loc[8]; unsigned s = 0;
    #pragma unroll
    for (int k = 0; k < 8; ++k) {
        int idx = tid * 8 + k;
        unsigned v = (idx < NB) ? h[idx] : 0u;
        loc[k] = s; s += v;
    }
    sc[tid] = s; __syncthreads();
    for (int off = 1; off < 256; off <<= 1) {
        unsigned a = (tid >= off) ? sc[tid - off] : 0u;
        __syncthreads(); sc[tid] += a; __syncthreads();
    }
    unsigned texcl = tid ? sc[tid - 1] : 0u;
    #pragma unroll
    for (int k = 0; k < 8; ++k) {
        int idx = tid * 8 + k;
        if (idx < NB) hloc[idx] = texcl + loc[k];
    }
    __syncthreads();

    for (int i = tid; i < NB; i += 256) hbase[i] = gbase[i] + pblk[(size_t)blk * NBP + i];
    __syncthreads();
    for (int i = tid; i < NB; i += 256) h[i] = 0;
    __syncthreads();

    #pragma unroll
    for (int t = 0; t < EPT; ++t) {
        if (es[t] >= 0) {
            int b = ed[t] >> 6;
            unsigned r = atomicAdd(&h[b], 1u);
            unsigned slot = hloc[b] + r;
            buf[slot] = (unsigned)es[t] | ((unsigned)(ed[t] & 63) << 17);
            buf2[slot] = hbase[b] + r;
        }
    }
    __syncthreads();

    for (int k = tid; k < csize; k += 256)
        pairs[buf2[k]] = buf[k];
}

// ---------------- place src local-ids into src-bucketed order (byte records) ----------------
__global__ __launch_bounds__(256) void placeS_kernel(const int* __restrict__ src,
                                                     const unsigned* __restrict__ gbase,
                                                     const unsigned* __restrict__ pblk,
                                                     unsigned char* __restrict__ pairs2, int nE) {
    __shared__ unsigned h[NB], hloc[NB], hbase[NB], sc[256];
    __shared__ unsigned char bufB[CHUNK];
    __shared__ unsigned buf2[CHUNK];
    int tid = threadIdx.x, blk = blockIdx.x;
    int e0 = blk * CHUNK;
    int csize = nE - e0; if (csize > CHUNK) csize = CHUNK;

    for (int i = tid; i < NB; i += 256) h[i] = 0;
    __syncthreads();

    int es[EPT];
    #pragma unroll
    for (int t = 0; t < EPT; ++t) {
        int e = e0 + t * 256 + tid;
        if (e < nE) { es[t] = src[e]; atomicAdd(&h[es[t] >> 6], 1u); }
        else es[t] = -1;
    }
    __syncthreads();

    unsigned loc[8]; unsigned s = 0;
    #pragma unroll
    for (int k = 0; k < 8; ++k) {
        int idx = tid * 8 + k;
        unsigned v = (idx < NB) ? h[idx] : 0u;
        loc[k] = s; s += v;
    }
    sc[tid] = s; __syncthreads();
    for (int off = 1; off < 256; off <<= 1) {
        unsigned a = (tid >= off) ? sc[tid - off] : 0u;
        __syncthreads(); sc[tid] += a; __syncthreads();
    }
    unsigned texcl = tid ? sc[tid - 1] : 0u;
    #pragma unroll
    for (int k = 0; k < 8; ++k) {
        int idx = tid * 8 + k;
        if (idx < NB) hloc[idx] = texcl + loc[k];
    }
    __syncthreads();

    for (int i = tid; i < NB; i += 256) hbase[i] = gbase[i] + pblk[(size_t)blk * NBP + i];
    __syncthreads();
    for (int i = tid; i < NB; i += 256) h[i] = 0;
    __syncthreads();

    #pragma unroll
    for (int t = 0; t < EPT; ++t) {
        if (es[t] >= 0) {
            int b = es[t] >> 6;
            unsigned r = atomicAdd(&h[b], 1u);
            unsigned slot = hloc[b] + r;
            bufB[slot] = (unsigned char)(es[t] & 63);
            buf2[slot] = hbase[b] + r;
        }
    }
    __syncthreads();

    for (int k = tid; k < csize; k += 256)
        pairs2[buf2[k]] = bufB[k];
}

// ---------------- out-degree per node from src-bucketed bytes -> ns = rsqrt ----------------
__global__ void srcdeg_kernel(const unsigned char* __restrict__ pairs2,
                              const unsigned* __restrict__ gbaseS,
                              const unsigned* __restrict__ totS,
                              float* __restrict__ nsb) {
    __shared__ unsigned cnt[BSZ];
    int tid = threadIdx.x, b = blockIdx.x;
    if (tid < BSZ) cnt[tid] = 0;
    __syncthreads();
    unsigned st = gbaseS[b];
    int n = (int)totS[b];
    for (int i = tid; i < n; i += 256)
        atomicAdd(&cnt[pairs2[st + i]], 1u);
    __syncthreads();
    if (tid < BSZ) {
        int node = b * BSZ + tid;
        if (node < NN) {
            unsigned c = cnt[tid]; if (c < 1u) c = 1u;
            nsb[node] = rsqrtf((float)c);
        }
    }
}

// ---------------- fp32 GEMM: hs[N,64] = (x[N,256] @ w[256,64]) * ns[row] ----------------
#define BM 128
#define BK 32
__global__ __launch_bounds__(256) void gemm_kernel(const float* __restrict__ x,
                                                   const float* __restrict__ w,
                                                   float* __restrict__ hs,
                                                   const float* __restrict__ ns) {
    __shared__ float xs[BK][BM];
    __shared__ float wsh[BK][FOUT];
    int tid = threadIdx.x;
    int m0 = blockIdx.x * BM;
    int tc = tid & 7;
    int tr = tid >> 3;
    float acc[4][8];
    #pragma unroll
    for (int i = 0; i < 4; i++)
        #pragma unroll
        for (int j = 0; j < 8; j++) acc[i][j] = 0.f;

    for (int k0 = 0; k0 < FIN; k0 += BK) {
        #pragma unroll
        for (int t = 0; t < 4; ++t) {
            int f = tid * 4 + t;
            int row = f >> 3;
            int kp = (f & 7) << 2;
            int gr = m0 + row;
            const float4 v = *(const float4*)&x[(size_t)(gr < NN ? gr : 0) * FIN + k0 + kp];
            xs[kp + 0][row] = v.x;
            xs[kp + 1][row] = v.y;
            xs[kp + 2][row] = v.z;
            xs[kp + 3][row] = v.w;
        }
        #pragma unroll
        for (int t = 0; t < 2; ++t) {
            int f = tid * 2 + t;
            int kk = f >> 4;
            int c = (f & 15) << 2;
            *(float4*)&wsh[kk][c] = *(const float4*)&w[(size_t)(k0 + kk) * FOUT + c];
        }
        __syncthreads();
        #pragma unroll
        for (int k = 0; k < BK; ++k) {
            float4 xv = *(const float4*)&xs[k][tr * 4];
            float4 w0 = *(const float4*)&wsh[k][tc * 8];
            float4 w1 = *(const float4*)&wsh[k][tc * 8 + 4];
            float xa[4] = {xv.x, xv.y, xv.z, xv.w};
            float wb[8] = {w0.x, w0.y, w0.z, w0.w, w1.x, w1.y, w1.z, w1.w};
            #pragma unroll
            for (int i = 0; i < 4; i++)
                #pragma unroll
                for (int j = 0; j < 8; j++)
                    acc[i][j] = fmaf(xa[i], wb[j], acc[i][j]);
        }
        __syncthreads();
    }
    #pragma unroll
    for (int i = 0; i < 4; i++) {
        int gr = m0 + tr * 4 + i;
        if (gr < NN) {
            float sc2 = ns[gr];
            float4 o0 = {acc[i][0] * sc2, acc[i][1] * sc2, acc[i][2] * sc2, acc[i][3] * sc2};
            float4 o1 = {acc[i][4] * sc2, acc[i][5] * sc2, acc[i][6] * sc2, acc[i][7] * sc2};
            *(float4*)&hs[(size_t)gr * FOUT + tc * 8] = o0;
            *(float4*)&hs[(size_t)gr * FOUT + tc * 8 + 4] = o1;
        }
    }
}

// ---------------- fused sort+aggregate: one block per 64-node bucket ----------------
template<bool LAST>
__global__ __launch_bounds__(512, 8) void aggsort_kernel(const unsigned* __restrict__ pairs,
                                                         const unsigned* __restrict__ gbase,
                                                         const unsigned* __restrict__ ghist,
                                                         const float* __restrict__ hs,
                                                         float* __restrict__ out) {
    __shared__ unsigned sorted[CAP];
    __shared__ unsigned cnt[BSZ];
    __shared__ unsigned loff[BSZ + 1];
    int tid = threadIdx.x;
    int b = blockIdx.x;
    int wave = tid >> 6, lane = tid & 63;

    unsigned start = gbase[b];
    int n = (int)ghist[b];

    if (n <= CAP) {
        if (tid < BSZ) cnt[tid] = 0;
        __syncthreads();
        unsigned rec[CAP / 512];
        #pragma unroll
        for (int t = 0; t < CAP / 512; ++t) {
            int i = t * 512 + tid;
            rec[t] = 0xFFFFFFFFu;
            if (i < n) {
                rec[t] = pairs[start + i];
                atomicAdd(&cnt[rec[t] >> 17], 1u);
            }
        }
        __syncthreads();
        if (wave == 0) {
            unsigned v = cnt[lane];
            unsigned sum = v;
            #pragma unroll
            for (int o = 1; o < 64; o <<= 1) {
                unsigned u = __shfl_up(sum, o);
                if (lane >= o) sum += u;
            }
            loff[lane + 1] = sum;
            if (lane == 0) loff[0] = 0;
            cnt[lane] = sum - v;
        }
        __syncthreads();
        #pragma unroll
        for (int t = 0; t < CAP / 512; ++t) {
            if (rec[t] != 0xFFFFFFFFu) {
                unsigned p = atomicAdd(&cnt[rec[t] >> 17], 1u);
                sorted[p] = rec[t];
            }
        }
        __syncthreads();

        for (int i = 0; i < 8; ++i) {
            int nl = wave * 8 + i;
            int node = b * BSZ + nl;
            if (node >= NN) break;
            int lo = (int)loff[nl], hi = (int)loff[nl + 1];
            float acc = 0.f;
            for (int base2 = lo; base2 < hi; base2 += 64) {
                int m = hi - base2; if (m > 64) m = 64;
                unsigned sl = (base2 + lane < hi) ? sorted[base2 + lane] : 0u;
                for (int j = 0; j < m; ++j) {
                    unsigned q = __shfl(sl, j);
                    acc += hs[(size_t)(q & 0x1FFFF) * FOUT + lane];
                }
            }
            int deg = hi - lo; if (deg < 1) deg = 1;
            float ndv = rsqrtf((float)deg);
            size_t oi = (size_t)node * FOUT + lane;
            float r = out[oi] + acc * ndv;
            out[oi] = LAST ? tanhf(r) : r;
        }
    } else {
        for (int i = 0; i < 8; ++i) {
            int nl = wave * 8 + i;
            int node = b * BSZ + nl;
            if (node >= NN) break;
            float acc = 0.f; int deg = 0;
            for (int base2 = 0; base2 < n; base2 += 64) {
                int m = n - base2; if (m > 64) m = 64;
                unsigned sl = (base2 + lane < n) ? pairs[start + base2 + lane] : 0xFFFFFFFFu;
                for (int j = 0; j < m; ++j) {
                    unsigned q = __shfl(sl, j);
                    if ((int)(q >> 17) == nl) {
                        acc += hs[(size_t)(q & 0x1FFFF) * FOUT + lane];
                        ++deg;
                    }
                }
            }
            if (deg < 1) deg = 1;
            float ndv = rsqrtf((float)deg);
            size_t oi = (size_t)node * FOUT + lane;
            float r = out[oi] + acc * ndv;
            out[oi] = LAST ? tanhf(r) : r;
        }
    }
}

extern "C" void kernel_launch(void* const* d_in, const int* in_sizes, int n_in,
                              void* d_out, int out_size, void* d_ws, size_t ws_size,
                              hipStream_t stream) {
    const float* x = (const float*)d_in[0];
    const float* W = (const float*)d_in[1];
    const int* ei = (const int*)d_in[2];
    float* out = (float*)d_out;

    char* ws = (char*)d_ws;
    size_t o = 0;
    float* hs = (float*)(ws + o);            o += (size_t)NN * FOUT * 4;        // 25.6 MB
    unsigned* pairs = (unsigned*)(ws + o);   o += (size_t)EPR * 4;              // 6.4 MB
    unsigned char* pairs2 = (unsigned char*)(ws + o); o += (size_t)EPR;         // 1.6 MB
    unsigned* btabD = (unsigned*)(ws + o);   o += (size_t)NBLK * NBP * 4;       // 2.45 MB
    unsigned* btabS = (unsigned*)(ws + o);   o += (size_t)NBLK * NBP * 4;       // 2.45 MB
    unsigned* totD = (unsigned*)(ws + o);    o += (size_t)NBP * 4;
    unsigned* totS = (unsigned*)(ws + o);    o += (size_t)NBP * 4;
    unsigned* gbaseD = (unsigned*)(ws + o);  o += (size_t)NBP * 4;
    unsigned* gbaseS = (unsigned*)(ws + o);  o += (size_t)NBP * 4;
    float* nsb = (float*)(ws + o);           o += (size_t)NN * 4;               // 0.4 MB

    hipMemsetAsync(d_out, 0, (size_t)out_size * sizeof(float), stream);

    for (int r = 0; r < 4; ++r) {
        const int* src = ei + (size_t)r * 2 * EPR;
        const int* dst = src + EPR;
        const float* w = W + (size_t)r * FIN * FOUT;

        hist_kernel<<<NBLK, 256, 0, stream>>>(src, dst, btabD, btabS, EPR);
        btot_kernel<<<dim3((NB + 7) / 8, 2), 256, 0, stream>>>(btabD, btabS, totD, totS);
        scan_nb2_kernel<<<2, 256, 0, stream>>>(totD, totS, gbaseD, gbaseS);
        placeD_kernel<<<NBLK, 256, 0, stream>>>(src, dst, gbaseD, btabD, pairs, EPR);
        placeS_kernel<<<NBLK, 256, 0, stream>>>(src, gbaseS, btabS, pairs2, EPR);
        srcdeg_kernel<<<NB, 256, 0, stream>>>(pairs2, gbaseS, totS, nsb);
        gemm_kernel<<<(NN + BM - 1) / BM, 256, 0, stream>>>(x, w, hs, nsb);
        if (r == 3)
            aggsort_kernel<true><<<NB, 512, 0, stream>>>(pairs, gbaseD, totD, hs, out);
        else
            aggsort_kernel<false><<<NB, 512, 0, stream>>>(pairs, gbaseD, totD, hs, out);
    }
}

// Round 10
// 576.300 us; speedup vs baseline: 6.8100x; 1.6067x over previous
//
#include <hip/hip_runtime.h>
#include <hip/hip_bf16.h>

#define NN 100000
#define EPR 1600000
#define FIN 256
#define FOUT 64
#define BSZ 64            // nodes per bucket
#define NB 1563           // ceil(100000/64)
#define NBP 1568          // padded row stride for block-bucket tables
#define CHUNK 4096
#define NBLK 391          // ceil(EPR/CHUNK)
#define EPT 16            // edges per thread in hist/place
#define CAP 4096          // max edges per bucket for LDS sort (mean 1024, sd 32)

typedef __attribute__((ext_vector_type(8))) short short8;
typedef __attribute__((ext_vector_type(4))) float f32x4;

__device__ __forceinline__ unsigned short f2bf(float f) {
    unsigned u = __float_as_uint(f);
    u = (u + 0x7FFFu + ((u >> 16) & 1u)) >> 16;   // RTN-even
    return (unsigned short)u;
}
__device__ __forceinline__ float bf2f(unsigned short v) {
    return __uint_as_float(((unsigned)v) << 16);
}

// ---------------- per-block bucket histograms (src & dst), no global atomics ----------------
__global__ __launch_bounds__(256) void hist_kernel(const int* __restrict__ src,
                                                   const int* __restrict__ dst,
                                                   unsigned* __restrict__ btabD,
                                                   unsigned* __restrict__ btabS, int nE) {
    __shared__ unsigned hD[NB], hS[NB];
    int tid = threadIdx.x;
    for (int i = tid; i < NB; i += 256) { hD[i] = 0; hS[i] = 0; }
    __syncthreads();
    int e0 = blockIdx.x * CHUNK;
    #pragma unroll
    for (int t = 0; t < EPT; ++t) {
        int e = e0 + t * 256 + tid;
        if (e < nE) {
            atomicAdd(&hS[src[e] >> 6], 1u);
            atomicAdd(&hD[dst[e] >> 6], 1u);
        }
    }
    __syncthreads();
    for (int i = tid; i < NB; i += 256) {
        btabD[(size_t)blockIdx.x * NBP + i] = hD[i];
        btabS[(size_t)blockIdx.x * NBP + i] = hS[i];
    }
}

// ---------------- per-bucket: exclusive scan over blocks (in place) + totals ----------------
__global__ __launch_bounds__(256) void btot_kernel(unsigned* __restrict__ btabD,
                                                   unsigned* __restrict__ btabS,
                                                   unsigned* __restrict__ totD,
                                                   unsigned* __restrict__ totS) {
    unsigned* tab = blockIdx.y ? btabS : btabD;
    unsigned* tot = blockIdx.y ? totS : totD;
    __shared__ unsigned tile[NBLK][8];
    int b0 = blockIdx.x * 8;
    for (int idx = threadIdx.x; idx < NBLK * 8; idx += 256) {
        int blk = idx >> 3, bb = idx & 7;
        int b = b0 + bb;
        tile[blk][bb] = (b < NB) ? tab[(size_t)blk * NBP + b] : 0u;
    }
    __syncthreads();
    if (threadIdx.x < 8) {
        int bb = threadIdx.x;
        unsigned s = 0;
        for (int blk = 0; blk < NBLK; ++blk) {
            unsigned v = tile[blk][bb];
            tile[blk][bb] = s;
            s += v;
        }
        if (b0 + bb < NB) tot[b0 + bb] = s;
    }
    __syncthreads();
    for (int idx = threadIdx.x; idx < NBLK * 8; idx += 256) {
        int blk = idx >> 3, bb = idx & 7;
        int b = b0 + bb;
        if (b < NB) tab[(size_t)blk * NBP + b] = tile[blk][bb];
    }
}

// ---------------- exclusive scan of bucket totals -> global bases (2 blocks: D,S) ----------------
__global__ void scan_nb2_kernel(const unsigned* __restrict__ totD, const unsigned* __restrict__ totS,
                                unsigned* __restrict__ gbaseD, unsigned* __restrict__ gbaseS) {
    const unsigned* tot = blockIdx.x ? totS : totD;
    unsigned* gb = blockIdx.x ? gbaseS : gbaseD;
    __shared__ unsigned sc[256];
    int tid = threadIdx.x;
    unsigned loc[8]; unsigned s = 0;
    #pragma unroll
    for (int k = 0; k < 8; ++k) {
        int idx = tid * 8 + k;
        unsigned v = (idx < NB) ? tot[idx] : 0u;
        loc[k] = s; s += v;
    }
    sc[tid] = s; __syncthreads();
    for (int off = 1; off < 256; off <<= 1) {
        unsigned a = (tid >= off) ? sc[tid - off] : 0u;
        __syncthreads(); sc[tid] += a; __syncthreads();
    }
    unsigned texcl = tid ? sc[tid - 1] : 0u;
    #pragma unroll
    for (int k = 0; k < 8; ++k) {
        int idx = tid * 8 + k;
        if (idx < NB) gb[idx] = texcl + loc[k];
    }
}

// ---------------- place edges into dst-bucketed order (deterministic, atomic-free global) ----------------
__global__ __launch_bounds__(256) void placeD_kernel(const int* __restrict__ src,
                                                     const int* __restrict__ dst,
                                                     const unsigned* __restrict__ gbase,
                                                     const unsigned* __restrict__ pblk,
                                                     unsigned* __restrict__ pairs, int nE) {
    __shared__ unsigned h[NB], hloc[NB], hbase[NB], sc[256];
    __shared__ unsigned buf[CHUNK], buf2[CHUNK];
    int tid = threadIdx.x, blk = blockIdx.x;
    int e0 = blk * CHUNK;
    int csize = nE - e0; if (csize > CHUNK) csize = CHUNK;

    for (int i = tid; i < NB; i += 256) h[i] = 0;
    __syncthreads();

    int es[EPT], ed[EPT];
    #pragma unroll
    for (int t = 0; t < EPT; ++t) {
        int e = e0 + t * 256 + tid;
        if (e < nE) { es[t] = src[e]; ed[t] = dst[e]; atomicAdd(&h[ed[t] >> 6], 1u); }
        else { es[t] = -1; ed[t] = 0; }
    }
    __syncthreads();

    unsigned loc[8]; unsigned s = 0;
    #pragma unroll
    for (int k = 0; k < 8; ++k) {
        int idx = tid * 8 + k;
        unsigned v = (idx < NB) ? h[idx] : 0u;
        loc[k] = s; s += v;
    }
    sc[tid] = s; __syncthreads();
    for (int off = 1; off < 256; off <<= 1) {
        unsigned a = (tid >= off) ? sc[tid - off] : 0u;
        __syncthreads(); sc[tid] += a; __syncthreads();
    }
    unsigned texcl = tid ? sc[tid - 1] : 0u;
    #pragma unroll
    for (int k = 0; k < 8; ++k) {
        int idx = tid * 8 + k;
        if (idx < NB) hloc[idx] = texcl + loc[k];
    }
    __syncthreads();

    for (int i = tid; i < NB; i += 256) hbase[i] = gbase[i] + pblk[(size_t)blk * NBP + i];
    __syncthreads();
    for (int i = tid; i < NB; i += 256) h[i] = 0;
    __syncthreads();

    #pragma unroll
    for (int t = 0; t < EPT; ++t) {
        if (es[t] >= 0) {
            int b = ed[t] >> 6;
            unsigned r = atomicAdd(&h[b], 1u);
            unsigned slot = hloc[b] + r;
            buf[slot] = (unsigned)es[t] | ((unsigned)(ed[t] & 63) << 17);
            buf2[slot] = hbase[b] + r;
        }
    }
    __syncthreads();

    for (int k = tid; k < csize; k += 256)
        pairs[buf2[k]] = buf[k];
}

// ---------------- place src local-ids into src-bucketed order (byte records) ----------------
__global__ __launch_bounds__(256) void placeS_kernel(const int* __restrict__ src,
                                                     const unsigned* __restrict__ gbase,
                                                     const unsigned* __restrict__ pblk,
                                                     unsigned char* __restrict__ pairs2, int nE) {
    __shared__ unsigned h[NB], hloc[NB], hbase[NB], sc[256];
    __shared__ unsigned char bufB[CHUNK];
    __shared__ unsigned buf2[CHUNK];
    int tid = threadIdx.x, blk = blockIdx.x;
    int e0 = blk * CHUNK;
    int csize = nE - e0; if (csize > CHUNK) csize = CHUNK;

    for (int i = tid; i < NB; i += 256) h[i] = 0;
    __syncthreads();

    int es[EPT];
    #pragma unroll
    for (int t = 0; t < EPT; ++t) {
        int e = e0 + t * 256 + tid;
        if (e < nE) { es[t] = src[e]; atomicAdd(&h[es[t] >> 6], 1u); }
        else es[t] = -1;
    }
    __syncthreads();

    unsigned loc[8]; unsigned s = 0;
    #pragma unroll
    for (int k = 0; k < 8; ++k) {
        int idx = tid * 8 + k;
        unsigned v = (idx < NB) ? h[idx] : 0u;
        loc[k] = s; s += v;
    }
    sc[tid] = s; __syncthreads();
    for (int off = 1; off < 256; off <<= 1) {
        unsigned a = (tid >= off) ? sc[tid - off] : 0u;
        __syncthreads(); sc[tid] += a; __syncthreads();
    }
    unsigned texcl = tid ? sc[tid - 1] : 0u;
    #pragma unroll
    for (int k = 0; k < 8; ++k) {
        int idx = tid * 8 + k;
        if (idx < NB) hloc[idx] = texcl + loc[k];
    }
    __syncthreads();

    for (int i = tid; i < NB; i += 256) hbase[i] = gbase[i] + pblk[(size_t)blk * NBP + i];
    __syncthreads();
    for (int i = tid; i < NB; i += 256) h[i] = 0;
    __syncthreads();

    #pragma unroll
    for (int t = 0; t < EPT; ++t) {
        if (es[t] >= 0) {
            int b = es[t] >> 6;
            unsigned r = atomicAdd(&h[b], 1u);
            unsigned slot = hloc[b] + r;
            bufB[slot] = (unsigned char)(es[t] & 63);
            buf2[slot] = hbase[b] + r;
        }
    }
    __syncthreads();

    for (int k = tid; k < csize; k += 256)
        pairs2[buf2[k]] = bufB[k];
}

// ---------------- out-degree per node from src-bucketed bytes -> ns = rsqrt ----------------
__global__ void srcdeg_kernel(const unsigned char* __restrict__ pairs2,
                              const unsigned* __restrict__ gbaseS,
                              const unsigned* __restrict__ totS,
                              float* __restrict__ nsb) {
    __shared__ unsigned cnt[BSZ];
    int tid = threadIdx.x, b = blockIdx.x;
    if (tid < BSZ) cnt[tid] = 0;
    __syncthreads();
    unsigned st = gbaseS[b];
    int n = (int)totS[b];
    for (int i = tid; i < n; i += 256)
        atomicAdd(&cnt[pairs2[st + i]], 1u);
    __syncthreads();
    if (tid < BSZ) {
        int node = b * BSZ + tid;
        if (node < NN) {
            unsigned c = cnt[tid]; if (c < 1u) c = 1u;
            nsb[node] = rsqrtf((float)c);
        }
    }
}

// ---------------- bf16 MFMA GEMM: hsb[N,64](bf16) = (x[N,256] @ w[256,64]) * ns[row] ----------------
// 128x64 tile, 4 waves in 2x2 grid (each 64m x 32n = 4x2 fragments of 16x16),
// K-step 32, fp32->bf16 convert during LDS staging. Row stride 40 (pad 8).
__global__ __launch_bounds__(256) void gemm_mfma_kernel(const float* __restrict__ x,
                                                        const float* __restrict__ w,
                                                        unsigned short* __restrict__ hsb,
                                                        const float* __restrict__ ns) {
    __shared__ unsigned short xs[128][40];   // [m][k] bf16
    __shared__ unsigned short wt[64][40];    // [n][k] bf16 (transposed W)
    int tid = threadIdx.x;
    int wave = tid >> 6, lane = tid & 63;
    int wm = (wave >> 1) * 64;
    int wn = (wave & 1) * 32;
    int m0 = blockIdx.x * 128;

    f32x4 acc[4][2];
    #pragma unroll
    for (int mi = 0; mi < 4; ++mi)
        #pragma unroll
        for (int ni = 0; ni < 2; ++ni)
            acc[mi][ni] = (f32x4){0.f, 0.f, 0.f, 0.f};

    int srow = tid >> 1, skp = (tid & 1) * 16;       // x staging coords
    int swn = tid >> 2, skq = (tid & 3) * 8;         // w staging coords
    int gr = m0 + srow; if (gr >= NN) gr = NN - 1;
    const float* xrow = &x[(size_t)gr * FIN];

    for (int k0 = 0; k0 < FIN; k0 += 32) {
        // stage x tile (coalesced float4 reads, packed bf16x4 LDS writes)
        #pragma unroll
        for (int q = 0; q < 4; ++q) {
            float4 v = *(const float4*)(xrow + k0 + skp + q * 4);
            unsigned lo = (unsigned)f2bf(v.x) | ((unsigned)f2bf(v.y) << 16);
            unsigned hi = (unsigned)f2bf(v.z) | ((unsigned)f2bf(v.w) << 16);
            *(uint2*)&xs[srow][skp + q * 4] = make_uint2(lo, hi);
        }
        // stage w tile transposed (w is tiny; strided reads hit LLC)
        {
            unsigned pk[4];
            #pragma unroll
            for (int i = 0; i < 8; i += 2) {
                unsigned short b0 = f2bf(w[(size_t)(k0 + skq + i) * FOUT + swn]);
                unsigned short b1 = f2bf(w[(size_t)(k0 + skq + i + 1) * FOUT + swn]);
                pk[i >> 1] = (unsigned)b0 | ((unsigned)b1 << 16);
            }
            *(uint4*)&wt[swn][skq] = make_uint4(pk[0], pk[1], pk[2], pk[3]);
        }
        __syncthreads();

        int fr = lane & 15, fk = (lane >> 4) * 8;
        short8 af[4], bfv[2];
        #pragma unroll
        for (int mi = 0; mi < 4; ++mi) af[mi] = *(const short8*)&xs[wm + mi * 16 + fr][fk];
        #pragma unroll
        for (int ni = 0; ni < 2; ++ni) bfv[ni] = *(const short8*)&wt[wn + ni * 16 + fr][fk];
        #pragma unroll
        for (int mi = 0; mi < 4; ++mi)
            #pragma unroll
            for (int ni = 0; ni < 2; ++ni)
                acc[mi][ni] = __builtin_amdgcn_mfma_f32_16x16x32_bf16(af[mi], bfv[ni], acc[mi][ni], 0, 0, 0);
        __syncthreads();
    }

    // epilogue: C/D layout col=lane&15, row=(lane>>4)*4+reg  [m89/m91]
    int fr = lane & 15, frow4 = (lane >> 4) * 4;
    #pragma unroll
    for (int mi = 0; mi < 4; ++mi) {
        #pragma unroll
        for (int rg = 0; rg < 4; ++rg) {
            int grow = m0 + wm + mi * 16 + frow4 + rg;
            if (grow < NN) {
                float sc2 = ns[grow];
                #pragma unroll
                for (int ni = 0; ni < 2; ++ni) {
                    int gcol = wn + ni * 16 + fr;
                    hsb[(size_t)grow * FOUT + gcol] = f2bf(acc[mi][ni][rg] * sc2);
                }
            }
        }
    }
}

// ---------------- fused sort+aggregate: one block per 64-node bucket ----------------
// Phase 1: counting-sort records into LDS. Phase 2: wave-per-node, register
// accumulation; record fetched by wave-uniform LDS broadcast (no shfl), bf16
// gathers (128B/row), fixed 8-deep unrolled inner loop.
template<bool LAST>
__global__ __launch_bounds__(512, 8) void aggsort_kernel(const unsigned* __restrict__ pairs,
                                                         const unsigned* __restrict__ gbase,
                                                         const unsigned* __restrict__ ghist,
                                                         const unsigned short* __restrict__ hsb,
                                                         float* __restrict__ out) {
    __shared__ unsigned sorted[CAP];
    __shared__ unsigned cnt[BSZ];
    __shared__ unsigned loff[BSZ + 1];
    int tid = threadIdx.x;
    int b = blockIdx.x;
    int wave = tid >> 6, lane = tid & 63;

    unsigned start = gbase[b];
    int n = (int)ghist[b];

    if (n <= CAP) {
        if (tid < BSZ) cnt[tid] = 0;
        __syncthreads();
        unsigned rec[CAP / 512];
        #pragma unroll
        for (int t = 0; t < CAP / 512; ++t) {
            int i = t * 512 + tid;
            rec[t] = 0xFFFFFFFFu;
            if (i < n) {
                rec[t] = pairs[start + i];
                atomicAdd(&cnt[rec[t] >> 17], 1u);
            }
        }
        __syncthreads();
        if (wave == 0) {
            unsigned v = cnt[lane];
            unsigned sum = v;
            #pragma unroll
            for (int o = 1; o < 64; o <<= 1) {
                unsigned u = __shfl_up(sum, o);
                if (lane >= o) sum += u;
            }
            loff[lane + 1] = sum;
            if (lane == 0) loff[0] = 0;
            cnt[lane] = sum - v;
        }
        __syncthreads();
        #pragma unroll
        for (int t = 0; t < CAP / 512; ++t) {
            if (rec[t] != 0xFFFFFFFFu) {
                unsigned p = atomicAdd(&cnt[rec[t] >> 17], 1u);
                sorted[p] = rec[t];
            }
        }
        __syncthreads();

        for (int i = 0; i < 8; ++i) {
            int nl = wave * 8 + i;
            int node = b * BSZ + nl;
            if (node >= NN) break;
            int lo = (int)loff[nl], hi = (int)loff[nl + 1];
            float acc = 0.f;
            for (int j0 = lo; j0 < hi; j0 += 8) {
                #pragma unroll
                for (int u = 0; u < 8; ++u) {
                    int j = j0 + u;
                    unsigned q = sorted[(j < hi) ? j : lo];   // wave-uniform LDS broadcast
                    float v = bf2f(hsb[(size_t)(q & 0x1FFFF) * FOUT + lane]);
                    acc += (j < hi) ? v : 0.f;
                }
            }
            int deg = hi - lo; if (deg < 1) deg = 1;
            float ndv = rsqrtf((float)deg);
            size_t oi = (size_t)node * FOUT + lane;
            float r = out[oi] + acc * ndv;
            out[oi] = LAST ? tanhf(r) : r;
        }
    } else {
        // overflow fallback (not expected for this input)
        for (int i = 0; i < 8; ++i) {
            int nl = wave * 8 + i;
            int node = b * BSZ + nl;
            if (node >= NN) break;
            float acc = 0.f; int deg = 0;
            for (int base2 = 0; base2 < n; base2 += 64) {
                int m = n - base2; if (m > 64) m = 64;
                unsigned sl = (base2 + lane < n) ? pairs[start + base2 + lane] : 0xFFFFFFFFu;
                for (int j = 0; j < m; ++j) {
                    unsigned q = __shfl(sl, j);
                    if ((int)(q >> 17) == nl) {
                        acc += bf2f(hsb[(size_t)(q & 0x1FFFF) * FOUT + lane]);
                        ++deg;
                    }
                }
            }
            if (deg < 1) deg = 1;
            float ndv = rsqrtf((float)deg);
            size_t oi = (size_t)node * FOUT + lane;
            float r = out[oi] + acc * ndv;
            out[oi] = LAST ? tanhf(r) : r;
        }
    }
}

extern "C" void kernel_launch(void* const* d_in, const int* in_sizes, int n_in,
                              void* d_out, int out_size, void* d_ws, size_t ws_size,
                              hipStream_t stream) {
    const float* x = (const float*)d_in[0];
    const float* W = (const float*)d_in[1];
    const int* ei = (const int*)d_in[2];
    float* out = (float*)d_out;

    char* ws = (char*)d_ws;
    size_t o = 0;
    unsigned short* hsb = (unsigned short*)(ws + o); o += (size_t)NN * FOUT * 2;  // 12.8 MB bf16
    unsigned* pairs = (unsigned*)(ws + o);   o += (size_t)EPR * 4;                // 6.4 MB
    unsigned char* pairs2 = (unsigned char*)(ws + o); o += (size_t)EPR;           // 1.6 MB
    unsigned* btabD = (unsigned*)(ws + o);   o += (size_t)NBLK * NBP * 4;         // 2.45 MB
    unsigned* btabS = (unsigned*)(ws + o);   o += (size_t)NBLK * NBP * 4;         // 2.45 MB
    unsigned* totD = (unsigned*)(ws + o);    o += (size_t)NBP * 4;
    unsigned* totS = (unsigned*)(ws + o);    o += (size_t)NBP * 4;
    unsigned* gbaseD = (unsigned*)(ws + o);  o += (size_t)NBP * 4;
    unsigned* gbaseS = (unsigned*)(ws + o);  o += (size_t)NBP * 4;
    float* nsb = (float*)(ws + o);           o += (size_t)NN * 4;                 // 0.4 MB

    hipMemsetAsync(d_out, 0, (size_t)out_size * sizeof(float), stream);

    for (int r = 0; r < 4; ++r) {
        const int* src = ei + (size_t)r * 2 * EPR;
        const int* dst = src + EPR;
        const float* w = W + (size_t)r * FIN * FOUT;

        hist_kernel<<<NBLK, 256, 0, stream>>>(src, dst, btabD, btabS, EPR);
        btot_kernel<<<dim3((NB + 7) / 8, 2), 256, 0, stream>>>(btabD, btabS, totD, totS);
        scan_nb2_kernel<<<2, 256, 0, stream>>>(totD, totS, gbaseD, gbaseS);
        placeD_kernel<<<NBLK, 256, 0, stream>>>(src, dst, gbaseD, btabD, pairs, EPR);
        placeS_kernel<<<NBLK, 256, 0, stream>>>(src, gbaseS, btabS, pairs2, EPR);
        srcdeg_kernel<<<NB, 256, 0, stream>>>(pairs2, gbaseS, totS, nsb);
        gemm_mfma_kernel<<<(NN + 127) / 128, 256, 0, stream>>>(x, w, hsb, nsb);
        if (r == 3)
            aggsort_kernel<true><<<NB, 512, 0, stream>>>(pairs, gbaseD, totD, hsb, out);
        else
            aggsort_kernel<false><<<NB, 512, 0, stream>>>(pairs, gbaseD, totD, hsb, out);
    }
}

// Round 11
// 415.389 us; speedup vs baseline: 9.4480x; 1.3874x over previous
//
#include <hip/hip_runtime.h>
#include <hip/hip_bf16.h>

#define NN 100000
#define EPR 1600000
#define FIN 256
#define FOUT 64
#define BSZ 64            // nodes per bucket
#define NB 1563           // ceil(100000/64)
#define NBP 1568          // padded row stride for tables
#define CHUNK 4096
#define NBLK 391          // ceil(EPR/CHUNK)
#define EPT 16            // edges per thread in hist/place
#define CAP 4096          // max edges per bucket for LDS sort (mean 1024, sd 32)

typedef __attribute__((ext_vector_type(8))) short short8;
typedef __attribute__((ext_vector_type(4))) float f32x4;

__device__ __forceinline__ unsigned short f2bf(float f) {
    unsigned u = __float_as_uint(f);
    u = (u + 0x7FFFu + ((u >> 16) & 1u)) >> 16;   // RTN-even
    return (unsigned short)u;
}
__device__ __forceinline__ float bf2f(unsigned short v) {
    return __uint_as_float(((unsigned)v) << 16);
}

// ---------------- per-(block,relation) bucket histograms ----------------
__global__ __launch_bounds__(256) void hist_all_kernel(const int* __restrict__ ei,
                                                       unsigned* __restrict__ btabD4,
                                                       unsigned* __restrict__ btabS4) {
    __shared__ unsigned hD[NB], hS[NB];
    int tid = threadIdx.x, r = blockIdx.y, blk = blockIdx.x;
    const int* src = ei + (size_t)r * 2 * EPR;
    const int* dst = src + EPR;
    for (int i = tid; i < NB; i += 256) { hD[i] = 0; hS[i] = 0; }
    __syncthreads();
    int e0 = blk * CHUNK;
    #pragma unroll
    for (int t = 0; t < EPT; ++t) {
        int e = e0 + t * 256 + tid;
        if (e < EPR) {
            atomicAdd(&hS[src[e] >> 6], 1u);
            atomicAdd(&hD[dst[e] >> 6], 1u);
        }
    }
    __syncthreads();
    size_t row = ((size_t)r * NBLK + blk) * NBP;
    for (int i = tid; i < NB; i += 256) {
        btabD4[row + i] = hD[i];
        btabS4[row + i] = hS[i];
    }
}

// ---------------- per-bucket exclusive scan over blocks + totals ----------------
__global__ __launch_bounds__(256) void btot_all_kernel(unsigned* __restrict__ btabD4,
                                                       unsigned* __restrict__ btabS4,
                                                       unsigned* __restrict__ totD4,
                                                       unsigned* __restrict__ totS4) {
    int r = blockIdx.z;
    unsigned* tab = (blockIdx.y ? btabS4 : btabD4) + (size_t)r * NBLK * NBP;
    unsigned* tot = (blockIdx.y ? totS4 : totD4) + (size_t)r * NBP;
    __shared__ unsigned tile[NBLK][8];
    int b0 = blockIdx.x * 8;
    for (int idx = threadIdx.x; idx < NBLK * 8; idx += 256) {
        int blk = idx >> 3, bb = idx & 7;
        int b = b0 + bb;
        tile[blk][bb] = (b < NB) ? tab[(size_t)blk * NBP + b] : 0u;
    }
    __syncthreads();
    if (threadIdx.x < 8) {
        int bb = threadIdx.x;
        unsigned s = 0;
        for (int blk = 0; blk < NBLK; ++blk) {
            unsigned v = tile[blk][bb];
            tile[blk][bb] = s;
            s += v;
        }
        if (b0 + bb < NB) tot[b0 + bb] = s;
    }
    __syncthreads();
    for (int idx = threadIdx.x; idx < NBLK * 8; idx += 256) {
        int blk = idx >> 3, bb = idx & 7;
        int b = b0 + bb;
        if (b < NB) tab[(size_t)blk * NBP + b] = tile[blk][bb];
    }
}

// ---------------- exclusive scan of bucket totals -> global bases ----------------
__global__ void scan_all_kernel(const unsigned* __restrict__ totD4, const unsigned* __restrict__ totS4,
                                unsigned* __restrict__ gbaseD4, unsigned* __restrict__ gbaseS4) {
    int r = blockIdx.y;
    const unsigned* tot = (blockIdx.x ? totS4 : totD4) + (size_t)r * NBP;
    unsigned* gb = (blockIdx.x ? gbaseS4 : gbaseD4) + (size_t)r * NBP;
    __shared__ unsigned sc[256];
    int tid = threadIdx.x;
    unsigned loc[8]; unsigned s = 0;
    #pragma unroll
    for (int k = 0; k < 8; ++k) {
        int idx = tid * 8 + k;
        unsigned v = (idx < NB) ? tot[idx] : 0u;
        loc[k] = s; s += v;
    }
    sc[tid] = s; __syncthreads();
    for (int off = 1; off < 256; off <<= 1) {
        unsigned a = (tid >= off) ? sc[tid - off] : 0u;
        __syncthreads(); sc[tid] += a; __syncthreads();
    }
    unsigned texcl = tid ? sc[tid - 1] : 0u;
    #pragma unroll
    for (int k = 0; k < 8; ++k) {
        int idx = tid * 8 + k;
        if (idx < NB) gb[idx] = texcl + loc[k];
    }
}

// ---------------- place edges into dst-bucketed order ----------------
__global__ __launch_bounds__(256) void placeD_all_kernel(const int* __restrict__ ei,
                                                         const unsigned* __restrict__ gbaseD4,
                                                         const unsigned* __restrict__ btabD4,
                                                         unsigned* __restrict__ pairs4) {
    __shared__ unsigned h[NB], hloc[NB], hbase[NB], sc[256];
    __shared__ unsigned buf[CHUNK], buf2[CHUNK];
    int tid = threadIdx.x, blk = blockIdx.x, r = blockIdx.y;
    const int* src = ei + (size_t)r * 2 * EPR;
    const int* dst = src + EPR;
    const unsigned* gbase = gbaseD4 + (size_t)r * NBP;
    const unsigned* pblk = btabD4 + ((size_t)r * NBLK + blk) * NBP;
    unsigned* pairs = pairs4 + (size_t)r * EPR;
    int e0 = blk * CHUNK;
    int csize = EPR - e0; if (csize > CHUNK) csize = CHUNK;

    for (int i = tid; i < NB; i += 256) h[i] = 0;
    __syncthreads();

    int es[EPT], ed[EPT];
    #pragma unroll
    for (int t = 0; t < EPT; ++t) {
        int e = e0 + t * 256 + tid;
        if (e < EPR) { es[t] = src[e]; ed[t] = dst[e]; atomicAdd(&h[ed[t] >> 6], 1u); }
        else { es[t] = -1; ed[t] = 0; }
    }
    __syncthreads();

    unsigned loc[8]; unsigned s = 0;
    #pragma unroll
    for (int k = 0; k < 8; ++k) {
        int idx = tid * 8 + k;
        unsigned v = (idx < NB) ? h[idx] : 0u;
        loc[k] = s; s += v;
    }
    sc[tid] = s; __syncthreads();
    for (int off = 1; off < 256; off <<= 1) {
        unsigned a = (tid >= off) ? sc[tid - off] : 0u;
        __syncthreads(); sc[tid] += a; __syncthreads();
    }
    unsigned texcl = tid ? sc[tid - 1] : 0u;
    #pragma unroll
    for (int k = 0; k < 8; ++k) {
        int idx = tid * 8 + k;
        if (idx < NB) hloc[idx] = texcl + loc[k];
    }
    __syncthreads();

    for (int i = tid; i < NB; i += 256) hbase[i] = gbase[i] + pblk[i];
    __syncthreads();
    for (int i = tid; i < NB; i += 256) h[i] = 0;
    __syncthreads();

    #pragma unroll
    for (int t = 0; t < EPT; ++t) {
        if (es[t] >= 0) {
            int b = ed[t] >> 6;
            unsigned rr = atomicAdd(&h[b], 1u);
            unsigned slot = hloc[b] + rr;
            buf[slot] = (unsigned)es[t] | ((unsigned)(ed[t] & 63) << 17);
            buf2[slot] = hbase[b] + rr;
        }
    }
    __syncthreads();

    for (int k = tid; k < csize; k += 256)
        pairs[buf2[k]] = buf[k];
}

// ---------------- place src local-ids into src-bucketed order (byte records) ----------------
__global__ __launch_bounds__(256) void placeS_all_kernel(const int* __restrict__ ei,
                                                         const unsigned* __restrict__ gbaseS4,
                                                         const unsigned* __restrict__ btabS4,
                                                         unsigned char* __restrict__ pairs2_4) {
    __shared__ unsigned h[NB], hloc[NB], hbase[NB], sc[256];
    __shared__ unsigned char bufB[CHUNK];
    __shared__ unsigned buf2[CHUNK];
    int tid = threadIdx.x, blk = blockIdx.x, r = blockIdx.y;
    const int* src = ei + (size_t)r * 2 * EPR;
    const unsigned* gbase = gbaseS4 + (size_t)r * NBP;
    const unsigned* pblk = btabS4 + ((size_t)r * NBLK + blk) * NBP;
    unsigned char* pairs2 = pairs2_4 + (size_t)r * EPR;
    int e0 = blk * CHUNK;
    int csize = EPR - e0; if (csize > CHUNK) csize = CHUNK;

    for (int i = tid; i < NB; i += 256) h[i] = 0;
    __syncthreads();

    int es[EPT];
    #pragma unroll
    for (int t = 0; t < EPT; ++t) {
        int e = e0 + t * 256 + tid;
        if (e < EPR) { es[t] = src[e]; atomicAdd(&h[es[t] >> 6], 1u); }
        else es[t] = -1;
    }
    __syncthreads();

    unsigned loc[8]; unsigned s = 0;
    #pragma unroll
    for (int k = 0; k < 8; ++k) {
        int idx = tid * 8 + k;
        unsigned v = (idx < NB) ? h[idx] : 0u;
        loc[k] = s; s += v;
    }
    sc[tid] = s; __syncthreads();
    for (int off = 1; off < 256; off <<= 1) {
        unsigned a = (tid >= off) ? sc[tid - off] : 0u;
        __syncthreads(); sc[tid] += a; __syncthreads();
    }
    unsigned texcl = tid ? sc[tid - 1] : 0u;
    #pragma unroll
    for (int k = 0; k < 8; ++k) {
        int idx = tid * 8 + k;
        if (idx < NB) hloc[idx] = texcl + loc[k];
    }
    __syncthreads();

    for (int i = tid; i < NB; i += 256) hbase[i] = gbase[i] + pblk[i];
    __syncthreads();
    for (int i = tid; i < NB; i += 256) h[i] = 0;
    __syncthreads();

    #pragma unroll
    for (int t = 0; t < EPT; ++t) {
        if (es[t] >= 0) {
            int b = es[t] >> 6;
            unsigned rr = atomicAdd(&h[b], 1u);
            unsigned slot = hloc[b] + rr;
            bufB[slot] = (unsigned char)(es[t] & 63);
            buf2[slot] = hbase[b] + rr;
        }
    }
    __syncthreads();

    for (int k = tid; k < csize; k += 256)
        pairs2[buf2[k]] = bufB[k];
}

// ---------------- out-degree per node -> ns = rsqrt ----------------
__global__ void srcdeg_all_kernel(const unsigned char* __restrict__ pairs2_4,
                                  const unsigned* __restrict__ gbaseS4,
                                  const unsigned* __restrict__ totS4,
                                  float* __restrict__ nsb4) {
    __shared__ unsigned cnt[BSZ];
    int tid = threadIdx.x, b = blockIdx.x, r = blockIdx.y;
    const unsigned char* pairs2 = pairs2_4 + (size_t)r * EPR;
    if (tid < BSZ) cnt[tid] = 0;
    __syncthreads();
    unsigned st = gbaseS4[(size_t)r * NBP + b];
    int n = (int)totS4[(size_t)r * NBP + b];
    for (int i = tid; i < n; i += 256)
        atomicAdd(&cnt[pairs2[st + i]], 1u);
    __syncthreads();
    if (tid < BSZ) {
        int node = b * BSZ + tid;
        if (node < NN) {
            unsigned c = cnt[tid]; if (c < 1u) c = 1u;
            nsb4[(size_t)r * NN + node] = rsqrtf((float)c);
        }
    }
}

// ---------------- fused 4-relation bf16 MFMA GEMM: x tile loaded ONCE ----------------
// 128x64 tile, 4 waves 2x2, K-step 32; acc[4 relations][4][2] f32x4 = 128 VGPR.
__global__ __launch_bounds__(256, 2) void gemm4_kernel(const float* __restrict__ x,
                                                       const float* __restrict__ W,
                                                       unsigned short* __restrict__ hsb4,
                                                       const float* __restrict__ nsb4) {
    __shared__ unsigned short xs[128][40];      // [m][k] bf16
    __shared__ unsigned short wt[4][64][40];    // [r][n][k] bf16
    int tid = threadIdx.x;
    int wave = tid >> 6, lane = tid & 63;
    int wm = (wave >> 1) * 64;
    int wn = (wave & 1) * 32;
    int m0 = blockIdx.x * 128;

    f32x4 acc[4][4][2];
    #pragma unroll
    for (int r = 0; r < 4; ++r)
        #pragma unroll
        for (int mi = 0; mi < 4; ++mi)
            #pragma unroll
            for (int ni = 0; ni < 2; ++ni)
                acc[r][mi][ni] = (f32x4){0.f, 0.f, 0.f, 0.f};

    int srow = tid >> 1, skp = (tid & 1) * 16;
    int swn = tid >> 2, skq = (tid & 3) * 8;
    int gr = m0 + srow; if (gr >= NN) gr = NN - 1;
    const float* xrow = &x[(size_t)gr * FIN];

    for (int k0 = 0; k0 < FIN; k0 += 32) {
        #pragma unroll
        for (int q = 0; q < 4; ++q) {
            float4 v = *(const float4*)(xrow + k0 + skp + q * 4);
            unsigned lo = (unsigned)f2bf(v.x) | ((unsigned)f2bf(v.y) << 16);
            unsigned hi = (unsigned)f2bf(v.z) | ((unsigned)f2bf(v.w) << 16);
            *(uint2*)&xs[srow][skp + q * 4] = make_uint2(lo, hi);
        }
        #pragma unroll
        for (int r = 0; r < 4; ++r) {
            const float* w = W + (size_t)r * FIN * FOUT;
            unsigned pk[4];
            #pragma unroll
            for (int i = 0; i < 8; i += 2) {
                unsigned short b0 = f2bf(w[(size_t)(k0 + skq + i) * FOUT + swn]);
                unsigned short b1 = f2bf(w[(size_t)(k0 + skq + i + 1) * FOUT + swn]);
                pk[i >> 1] = (unsigned)b0 | ((unsigned)b1 << 16);
            }
            *(uint4*)&wt[r][swn][skq] = make_uint4(pk[0], pk[1], pk[2], pk[3]);
        }
        __syncthreads();

        int fr = lane & 15, fk = (lane >> 4) * 8;
        short8 af[4];
        #pragma unroll
        for (int mi = 0; mi < 4; ++mi) af[mi] = *(const short8*)&xs[wm + mi * 16 + fr][fk];
        #pragma unroll
        for (int r = 0; r < 4; ++r) {
            short8 b0 = *(const short8*)&wt[r][wn + fr][fk];
            short8 b1 = *(const short8*)&wt[r][wn + 16 + fr][fk];
            #pragma unroll
            for (int mi = 0; mi < 4; ++mi) {
                acc[r][mi][0] = __builtin_amdgcn_mfma_f32_16x16x32_bf16(af[mi], b0, acc[r][mi][0], 0, 0, 0);
                acc[r][mi][1] = __builtin_amdgcn_mfma_f32_16x16x32_bf16(af[mi], b1, acc[r][mi][1], 0, 0, 0);
            }
        }
        __syncthreads();
    }

    // epilogue: C/D layout col=lane&15, row=(lane>>4)*4+reg
    int fr = lane & 15, frow4 = (lane >> 4) * 4;
    #pragma unroll
    for (int r = 0; r < 4; ++r) {
        unsigned short* hsb = hsb4 + (size_t)r * NN * FOUT;
        const float* ns = nsb4 + (size_t)r * NN;
        #pragma unroll
        for (int mi = 0; mi < 4; ++mi) {
            #pragma unroll
            for (int rg = 0; rg < 4; ++rg) {
                int grow = m0 + wm + mi * 16 + frow4 + rg;
                if (grow < NN) {
                    float sc2 = ns[grow];
                    #pragma unroll
                    for (int ni = 0; ni < 2; ++ni) {
                        int gcol = wn + ni * 16 + fr;
                        hsb[(size_t)grow * FOUT + gcol] = f2bf(acc[r][mi][ni][rg] * sc2);
                    }
                }
            }
        }
    }
}

// ---------------- fused 4-relation sort+aggregate; out written ONCE ----------------
__global__ __launch_bounds__(512, 8) void aggsort4_kernel(const unsigned* __restrict__ pairs4,
                                                          const unsigned* __restrict__ gbaseD4,
                                                          const unsigned* __restrict__ totD4,
                                                          const unsigned short* __restrict__ hsb4,
                                                          float* __restrict__ out) {
    __shared__ unsigned sorted[CAP];
    __shared__ unsigned cnt[BSZ];
    __shared__ unsigned loff[BSZ + 1];
    int tid = threadIdx.x;
    int b = blockIdx.x;
    int wave = tid >> 6, lane = tid & 63;

    float acc[8];
    #pragma unroll
    for (int i = 0; i < 8; ++i) acc[i] = 0.f;

    for (int r = 0; r < 4; ++r) {
        const unsigned* pairs = pairs4 + (size_t)r * EPR;
        const unsigned short* hsb = hsb4 + (size_t)r * NN * FOUT;
        unsigned start = gbaseD4[(size_t)r * NBP + b];
        int n = (int)totD4[(size_t)r * NBP + b];

        __syncthreads();                 // protect sorted/cnt reuse from prev r
        if (tid < BSZ) cnt[tid] = 0;
        __syncthreads();

        if (n <= CAP) {
            unsigned rec[CAP / 512];
            #pragma unroll
            for (int t = 0; t < CAP / 512; ++t) {
                int i = t * 512 + tid;
                rec[t] = 0xFFFFFFFFu;
                if (i < n) {
                    rec[t] = pairs[start + i];
                    atomicAdd(&cnt[rec[t] >> 17], 1u);
                }
            }
            __syncthreads();
            if (wave == 0) {
                unsigned v = cnt[lane];
                unsigned sum = v;
                #pragma unroll
                for (int o = 1; o < 64; o <<= 1) {
                    unsigned u = __shfl_up(sum, o);
                    if (lane >= o) sum += u;
                }
                loff[lane + 1] = sum;
                if (lane == 0) loff[0] = 0;
                cnt[lane] = sum - v;
            }
            __syncthreads();
            #pragma unroll
            for (int t = 0; t < CAP / 512; ++t) {
                if (rec[t] != 0xFFFFFFFFu) {
                    unsigned p = atomicAdd(&cnt[rec[t] >> 17], 1u);
                    sorted[p] = rec[t];
                }
            }
            __syncthreads();

            for (int i = 0; i < 8; ++i) {
                int nl = wave * 8 + i;
                int node = b * BSZ + nl;
                if (node >= NN) break;
                int lo = (int)loff[nl], hi = (int)loff[nl + 1];
                float seg = 0.f;
                for (int j0 = lo; j0 < hi; j0 += 8) {
                    #pragma unroll
                    for (int u = 0; u < 8; ++u) {
                        int j = j0 + u;
                        unsigned q = sorted[(j < hi) ? j : lo];   // wave-uniform broadcast
                        float v = bf2f(hsb[(size_t)(q & 0x1FFFF) * FOUT + lane]);
                        seg += (j < hi) ? v : 0.f;
                    }
                }
                int deg = hi - lo; if (deg < 1) deg = 1;
                acc[i] += seg * rsqrtf((float)deg);
            }
        } else {
            // overflow fallback (not expected): scan-all per node
            for (int i = 0; i < 8; ++i) {
                int nl = wave * 8 + i;
                int node = b * BSZ + nl;
                if (node >= NN) break;
                float seg = 0.f; int deg = 0;
                for (int base2 = 0; base2 < n; base2 += 64) {
                    int m = n - base2; if (m > 64) m = 64;
                    unsigned sl = (base2 + lane < n) ? pairs[start + base2 + lane] : 0xFFFFFFFFu;
                    for (int j = 0; j < m; ++j) {
                        unsigned q = __shfl(sl, j);
                        if ((int)(q >> 17) == nl) {
                            seg += bf2f(hsb[(size_t)(q & 0x1FFFF) * FOUT + lane]);
                            ++deg;
                        }
                    }
                }
                if (deg < 1) deg = 1;
                acc[i] += seg * rsqrtf((float)deg);
            }
        }
    }

    #pragma unroll
    for (int i = 0; i < 8; ++i) {
        int nl = wave * 8 + i;
        int node = b * BSZ + nl;
        if (node < NN)
            out[(size_t)node * FOUT + lane] = tanhf(acc[i]);
    }
}

extern "C" void kernel_launch(void* const* d_in, const int* in_sizes, int n_in,
                              void* d_out, int out_size, void* d_ws, size_t ws_size,
                              hipStream_t stream) {
    const float* x = (const float*)d_in[0];
    const float* W = (const float*)d_in[1];
    const int* ei = (const int*)d_in[2];
    float* out = (float*)d_out;

    char* ws = (char*)d_ws;
    size_t o = 0;
    unsigned short* hsb4 = (unsigned short*)(ws + o); o += (size_t)4 * NN * FOUT * 2;  // 51.2 MB
    unsigned* pairs4 = (unsigned*)(ws + o);   o += (size_t)4 * EPR * 4;                // 25.6 MB
    unsigned char* pairs2_4 = (unsigned char*)(ws + o); o += (size_t)4 * EPR;          // 6.4 MB
    unsigned* btabD4 = (unsigned*)(ws + o);   o += (size_t)4 * NBLK * NBP * 4;         // 9.8 MB
    unsigned* btabS4 = (unsigned*)(ws + o);   o += (size_t)4 * NBLK * NBP * 4;         // 9.8 MB
    unsigned* totD4 = (unsigned*)(ws + o);    o += (size_t)4 * NBP * 4;
    unsigned* totS4 = (unsigned*)(ws + o);    o += (size_t)4 * NBP * 4;
    unsigned* gbaseD4 = (unsigned*)(ws + o);  o += (size_t)4 * NBP * 4;
    unsigned* gbaseS4 = (unsigned*)(ws + o);  o += (size_t)4 * NBP * 4;
    float* nsb4 = (float*)(ws + o);           o += (size_t)4 * NN * 4;                 // 1.6 MB

    hist_all_kernel<<<dim3(NBLK, 4), 256, 0, stream>>>(ei, btabD4, btabS4);
    btot_all_kernel<<<dim3((NB + 7) / 8, 2, 4), 256, 0, stream>>>(btabD4, btabS4, totD4, totS4);
    scan_all_kernel<<<dim3(2, 4), 256, 0, stream>>>(totD4, totS4, gbaseD4, gbaseS4);
    placeD_all_kernel<<<dim3(NBLK, 4), 256, 0, stream>>>(ei, gbaseD4, btabD4, pairs4);
    placeS_all_kernel<<<dim3(NBLK, 4), 256, 0, stream>>>(ei, gbaseS4, btabS4, pairs2_4);
    srcdeg_all_kernel<<<dim3(NB, 4), 256, 0, stream>>>(pairs2_4, gbaseS4, totS4, nsb4);
    gemm4_kernel<<<(NN + 127) / 128, 256, 0, stream>>>(x, W, hsb4, nsb4);
    aggsort4_kernel<<<NB, 512, 0, stream>>>(pairs4, gbaseD4, totD4, hsb4, out);
}